// Round 7
// baseline (715.755 us; speedup 1.0000x reference)
//
#include <hip/hip_runtime.h>

#define B_ 16
#define N_ 1024
#define F_ 768
#define H_ 128

typedef float f32x4 __attribute__((ext_vector_type(4)));
typedef short s16x8 __attribute__((ext_vector_type(8)));
typedef unsigned short u16;
typedef u16 u16x8 __attribute__((ext_vector_type(8)));
typedef u16 u16x4 __attribute__((ext_vector_type(4)));

__device__ __forceinline__ u16 f2b(float f) {
  unsigned u = __float_as_uint(f);
  unsigned r = (u + 0x7FFFu + ((u >> 16) & 1u)) >> 16;
  return (u16)r;
}
__device__ __forceinline__ float b2f(u16 u) {
  return __uint_as_float(((unsigned)u) << 16);
}

__device__ __forceinline__ void gload16(const u16* g, u16* l) {
  __builtin_amdgcn_global_load_lds(
      (const __attribute__((address_space(1))) unsigned int*)g,
      (__attribute__((address_space(3))) unsigned int*)l, 16, 0, 0);
}

// ---------------------------------------------------------------------------
__device__ __forceinline__ float blockReduceSum256(float v) {
  __shared__ float red[4];
  #pragma unroll
  for (int o = 32; o > 0; o >>= 1) v += __shfl_down(v, o, 64);
  if ((threadIdx.x & 63) == 0) red[threadIdx.x >> 6] = v;
  __syncthreads();
  float r = red[0] + red[1] + red[2] + red[3];
  __syncthreads();
  return r;
}

// ---------------------------------------------------------------------------
// K1: degrees + fused adjT bf16 emission (column scatter, L2-merged)
// ---------------------------------------------------------------------------
__global__ __launch_bounds__(256) void k_degrees(
    const float* __restrict__ adj, float* __restrict__ dis_bin,
    float* __restrict__ dr, float* __restrict__ dc, u16* __restrict__ adjT) {
  long row = blockIdx.x;
  int b = (int)(row >> 10), i = (int)(row & 1023);
  const float* a = adj + row * N_;
  u16* aT = adjT + (long)b * (long)N_ * N_ + i;
  float cnt = 0.f, sw = 0.f;
  for (int j = threadIdx.x; j < N_; j += 256) {
    float v = a[j];
    aT[(long)j * N_] = f2b(v);
    if (v != 0.0f) { cnt += 1.0f; sw += v; }
  }
  __shared__ float r1[4], r2[4];
  #pragma unroll
  for (int o = 32; o > 0; o >>= 1) { cnt += __shfl_down(cnt, o, 64); sw += __shfl_down(sw, o, 64); }
  if ((threadIdx.x & 63) == 0) { r1[threadIdx.x >> 6] = cnt; r2[threadIdx.x >> 6] = sw; }
  __syncthreads();
  if (threadIdx.x == 0) {
    float c = r1[0] + r1[1] + r1[2] + r1[3];
    float s = r2[0] + r2[1] + r2[2] + r2[3];
    dis_bin[row] = rsqrtf(c + 1.0f);
    float d = rsqrtf(s + 1.0f);
    dc[row] = d;
    dr[row] = (s > 0.0f) ? d : 0.0f;
  }
}

// ---------------------------------------------------------------------------
// split f32 -> 3 bf16 planes
// ---------------------------------------------------------------------------
__global__ __launch_bounds__(256) void k_split3(
    const float* __restrict__ X, u16* __restrict__ Yh, u16* __restrict__ Ym,
    u16* __restrict__ Yl, long n4) {
  long i = (long)blockIdx.x * 256 + threadIdx.x;
  long stride = (long)gridDim.x * 256;
  for (; i < n4; i += stride) {
    f32x4 v = *(const f32x4*)(X + i * 4);
    u16x4 oh, om, ol;
    #pragma unroll
    for (int e = 0; e < 4; ++e) {
      float f = v[e];
      u16 h = f2b(f); float r1 = f - b2f(h);
      u16 m = f2b(r1); float r2 = r1 - b2f(m);
      u16 l = f2b(r2);
      oh[e] = h; om[e] = m; ol[e] = l;
    }
    *(u16x4*)(Yh + i * 4) = oh;
    *(u16x4*)(Ym + i * 4) = om;
    *(u16x4*)(Yl + i * 4) = ol;
  }
}

// transpose W1 [F][H] -> [H][F] with 3-way split
__global__ __launch_bounds__(256) void k_convT3(
    const float* __restrict__ X, u16* __restrict__ Yh, u16* __restrict__ Ym,
    u16* __restrict__ Yl) {
  __shared__ float tile[32][33];
  int tx = threadIdx.x & 31, ty = threadIdx.x >> 5;
  int r0 = blockIdx.y * 32, c0 = blockIdx.x * 32;
  #pragma unroll
  for (int i = 0; i < 4; ++i)
    tile[ty + i * 8][tx] = X[(long)(r0 + ty + i * 8) * H_ + (c0 + tx)];
  __syncthreads();
  #pragma unroll
  for (int i = 0; i < 4; ++i) {
    float v = tile[tx][ty + i * 8];
    long o = (long)(c0 + ty + i * 8) * F_ + (r0 + tx);
    u16 h = f2b(v); float r1 = v - b2f(h);
    u16 m = f2b(r1); float r2 = r1 - b2f(m);
    u16 l = f2b(r2);
    Yh[o] = h; Ym[o] = m; Yl[o] = l;
  }
}

// ---------------------------------------------------------------------------
// G1: P1raw = (A0+A1+A2) @ (B0+B1+B2)^T  (6-product split-3 MFMA, unscaled)
// ---------------------------------------------------------------------------
__global__ __launch_bounds__(256) void mgemm64s3(
    const u16* __restrict__ A0, const u16* __restrict__ A1, const u16* __restrict__ A2,
    const u16* __restrict__ B0, const u16* __restrict__ B1, const u16* __restrict__ B2,
    float* __restrict__ C, int N, int K) {
  int m0 = blockIdx.y * 64, n0 = blockIdx.x * 64;
  __shared__ __align__(16) u16 As[3][64 * 72];
  __shared__ __align__(16) u16 Bs[3][64 * 72];
  const u16* Ap[3] = {A0 + (long)m0 * K, A1 + (long)m0 * K, A2 + (long)m0 * K};
  const u16* Bp[3] = {B0 + (long)n0 * K, B1 + (long)n0 * K, B2 + (long)n0 * K};
  int tid = threadIdx.x, lane = tid & 63, wave = tid >> 6;
  int wr = wave >> 1, wc = wave & 1, kg = lane >> 4, r16 = lane & 15;
  f32x4 acc[2][2] = {};

  for (int k0 = 0; k0 < K; k0 += 64) {
    #pragma unroll
    for (int t = 0; t < 3; ++t) {
      #pragma unroll
      for (int i = 0; i < 2; ++i) {
        int u = tid + i * 256;
        int row = u >> 3, seg = u & 7;
        *(u16x8*)(&As[t][row * 72 + seg * 8]) = *(const u16x8*)(Ap[t] + (long)row * K + k0 + seg * 8);
        *(u16x8*)(&Bs[t][row * 72 + seg * 8]) = *(const u16x8*)(Bp[t] + (long)row * K + k0 + seg * 8);
      }
    }
    __syncthreads();
    #pragma unroll
    for (int kk = 0; kk < 2; ++kk) {
      s16x8 ah[2], am[2], al[2], bh[2], bm[2], bl[2];
      #pragma unroll
      for (int m = 0; m < 2; ++m) {
        int off = (wr * 32 + m * 16 + r16) * 72 + kk * 32 + kg * 8;
        ah[m] = *(const s16x8*)(&As[0][off]);
        am[m] = *(const s16x8*)(&As[1][off]);
        al[m] = *(const s16x8*)(&As[2][off]);
      }
      #pragma unroll
      for (int n = 0; n < 2; ++n) {
        int off = (wc * 32 + n * 16 + r16) * 72 + kk * 32 + kg * 8;
        bh[n] = *(const s16x8*)(&Bs[0][off]);
        bm[n] = *(const s16x8*)(&Bs[1][off]);
        bl[n] = *(const s16x8*)(&Bs[2][off]);
      }
      #pragma unroll
      for (int m = 0; m < 2; ++m)
        #pragma unroll
        for (int n = 0; n < 2; ++n) {
          acc[m][n] = __builtin_amdgcn_mfma_f32_16x16x32_bf16(ah[m], bh[n], acc[m][n], 0, 0, 0);
          acc[m][n] = __builtin_amdgcn_mfma_f32_16x16x32_bf16(ah[m], bm[n], acc[m][n], 0, 0, 0);
          acc[m][n] = __builtin_amdgcn_mfma_f32_16x16x32_bf16(am[m], bh[n], acc[m][n], 0, 0, 0);
          acc[m][n] = __builtin_amdgcn_mfma_f32_16x16x32_bf16(am[m], bm[n], acc[m][n], 0, 0, 0);
          acc[m][n] = __builtin_amdgcn_mfma_f32_16x16x32_bf16(ah[m], bl[n], acc[m][n], 0, 0, 0);
          acc[m][n] = __builtin_amdgcn_mfma_f32_16x16x32_bf16(al[m], bh[n], acc[m][n], 0, 0, 0);
        }
    }
    __syncthreads();
  }

  #pragma unroll
  for (int m = 0; m < 2; ++m)
    #pragma unroll
    for (int r = 0; r < 4; ++r) {
      int row = m0 + wr * 32 + m * 16 + kg * 4 + r;
      #pragma unroll
      for (int n = 0; n < 2; ++n) {
        int col = n0 + wc * 32 + n * 16 + r16;
        C[(long)row * N + col] = acc[m][n][r];
      }
    }
}

// ---------------------------------------------------------------------------
// K2: x1 = relu(dis_i*(sum_{adj_ij!=0} dis_j*P1raw_j + dis_i*P1raw_i) + b1)
// fused x1T bf16 emission.  (dis scaling moved here since G1 is unscaled)
// ---------------------------------------------------------------------------
__global__ __launch_bounds__(256) void k_spmm_relu(
    const float* __restrict__ adj, const float* __restrict__ P1,
    const float* __restrict__ dis_bin, const float* __restrict__ b1,
    float* __restrict__ x1, u16* __restrict__ x1T) {
  long row = blockIdx.x;
  int b = (int)(row >> 10), i = (int)(row & 1023);
  const float* a = adj + row * N_;
  const float* Pb = P1 + (long)b * (long)N_ * H_;
  const float* db = dis_bin + (long)b * N_;
  __shared__ int idxs[N_];
  __shared__ int tcnt[256];
  __shared__ float accs[H_];
  int tid = threadIdx.x;
  int base = tid * 4;
  f32x4 av = *(const f32x4*)(a + base);
  int c0 = (av[0] != 0.0f) + (av[1] != 0.0f) + (av[2] != 0.0f) + (av[3] != 0.0f);
  tcnt[tid] = c0;
  __syncthreads();
  for (int off = 1; off < 256; off <<= 1) {
    int add = (tid >= off) ? tcnt[tid - off] : 0;
    __syncthreads();
    tcnt[tid] += add;
    __syncthreads();
  }
  int pos = tcnt[tid] - c0;
  int n = tcnt[255];
  if (av[0] != 0.0f) idxs[pos++] = base;
  if (av[1] != 0.0f) idxs[pos++] = base + 1;
  if (av[2] != 0.0f) idxs[pos++] = base + 2;
  if (av[3] != 0.0f) idxs[pos++] = base + 3;
  __syncthreads();
  int c = tid & 127, team = tid >> 7;
  float acc = 0.f;
  for (int u = team; u < n; u += 2) {
    int j = idxs[u];
    acc += db[j] * Pb[(long)j * H_ + c];
  }
  if (team == 1) accs[c] = acc;
  __syncthreads();
  if (team == 0) {
    float di = db[i];
    float tot = acc + accs[c] + di * Pb[(long)i * H_ + c];
    float v = di * tot + b1[c];
    v = fmaxf(v, 0.0f);
    x1[row * H_ + c] = v;
    x1T[(long)b * (long)N_ * H_ + (long)c * N_ + i] = f2b(v);
  }
}

// ---------------------------------------------------------------------------
// Big MFMA GEMM: 128x128 tile, BK=32, global_load_lds staging.
// MODE 1: bf16 C | 2: floorq + rowcnt + cbin | 3: tanh(sc*(acc+Add)+bias) |
// 4: scale[row]*acc
// ---------------------------------------------------------------------------
template<int MODE>
__global__ __launch_bounds__(256) void mgemm(
    const u16* __restrict__ A, const u16* __restrict__ Bt, void* __restrict__ Cv,
    int M, int N, int K, long sA, long sB, long sC,
    const float* __restrict__ scale, const float* __restrict__ Add, long sAdd,
    const float* __restrict__ bias, int* __restrict__ rowcnt,
    u16* __restrict__ cbin) {
  int bz = blockIdx.z;
  int m0 = blockIdx.y * 128, n0 = blockIdx.x * 128;
  const u16* Ab = A + (long)bz * sA + (long)m0 * K;
  const u16* Bb = Bt + (long)bz * sB + (long)n0 * K;
  __shared__ __align__(16) u16 As[128 * 32];
  __shared__ __align__(16) u16 Bs[128 * 32];
  int tid = threadIdx.x;
  int lane = tid & 63, wave = tid >> 6;
  int wr = wave >> 1, wc = wave & 1;
  int kg = lane >> 4, r16 = lane & 15;
  const u16* ga = Ab + (long)(tid >> 2) * K + (tid & 3) * 8;
  const u16* gb = Bb + (long)(tid >> 2) * K + (tid & 3) * 8;
  f32x4 acc[4][4] = {};

  for (int k0 = 0; k0 < K; k0 += 32) {
    gload16(ga + k0, &As[tid * 8]);
    gload16(ga + (long)64 * K + k0, &As[2048 + tid * 8]);
    gload16(gb + k0, &Bs[tid * 8]);
    gload16(gb + (long)64 * K + k0, &Bs[2048 + tid * 8]);
    __syncthreads();
    s16x8 af[4], bfr[4];
    #pragma unroll
    for (int m = 0; m < 4; ++m)
      af[m] = *(const s16x8*)(&As[(wr * 64 + m * 16 + r16) * 32 + kg * 8]);
    #pragma unroll
    for (int n = 0; n < 4; ++n)
      bfr[n] = *(const s16x8*)(&Bs[(wc * 64 + n * 16 + r16) * 32 + kg * 8]);
    #pragma unroll
    for (int m = 0; m < 4; ++m)
      #pragma unroll
      for (int n = 0; n < 4; ++n)
        acc[m][n] = __builtin_amdgcn_mfma_f32_16x16x32_bf16(af[m], bfr[n], acc[m][n], 0, 0, 0);
    __syncthreads();
  }

  if constexpr (MODE == 2) {
    int* cnt = (int*)As;
    if (tid < 128) cnt[tid] = 0;
    __syncthreads();
    #pragma unroll
    for (int m = 0; m < 4; ++m) {
      #pragma unroll
      for (int r = 0; r < 4; ++r) {
        int lrow = wr * 64 + m * 16 + kg * 4 + r;
        int row = m0 + lrow;
        int nz = 0;
        #pragma unroll
        for (int n = 0; n < 4; ++n) {
          int col = n0 + wc * 64 + n * 16 + r16;
          float q = floorf(acc[m][n][r] * 10000.0f) / 10000.0f;
          long cidx = (long)bz * sC + (long)row * N + col;
          ((float*)Cv)[cidx] = q;
          cbin[cidx] = (q != 0.0f) ? (u16)0x3F80 : (u16)0;
          nz += (q != 0.0f) ? 1 : 0;
        }
        atomicAdd(&cnt[lrow], nz);
      }
    }
    __syncthreads();
    if (tid < 128) atomicAdd(&rowcnt[(long)bz * N_ + m0 + tid], cnt[tid]);
    return;
  }

  #pragma unroll
  for (int m = 0; m < 4; ++m) {
    #pragma unroll
    for (int r = 0; r < 4; ++r) {
      int row = m0 + wr * 64 + m * 16 + kg * 4 + r;
      float sc = 0.f;
      if constexpr (MODE == 3) sc = scale[(long)bz * N_ + row];
      if constexpr (MODE == 4) sc = scale[row];
      #pragma unroll
      for (int n = 0; n < 4; ++n) {
        int col = n0 + wc * 64 + n * 16 + r16;
        float v = acc[m][n][r];
        long cidx = (long)bz * sC + (long)row * N + col;
        if constexpr (MODE == 1) {
          ((u16*)Cv)[cidx] = f2b(v);
        } else if constexpr (MODE == 3) {
          v = sc * (v + Add[(long)bz * sAdd + (long)row * N + col]) + bias[col];
          ((float*)Cv)[cidx] = tanhf(v);
        } else if constexpr (MODE == 4) {
          ((float*)Cv)[cidx] = sc * v;
        } else {
          ((float*)Cv)[cidx] = v;
        }
      }
    }
  }
}

// ---------------------------------------------------------------------------
// Small-N MFMA GEMM: 64x64 tile, BK=64, reg-staged, pad-72 LDS.
// f32 C + optional bf16 mirror.
// ---------------------------------------------------------------------------
__global__ __launch_bounds__(256) void mgemm64(
    const u16* __restrict__ A, const u16* __restrict__ Bt, float* __restrict__ C,
    int N, int K, long sA, long sB, long sC, u16* __restrict__ Cbf) {
  int bz = blockIdx.z;
  int m0 = blockIdx.y * 64, n0 = blockIdx.x * 64;
  const u16* Ab = A + (long)bz * sA + (long)m0 * K;
  const u16* Bb = Bt + (long)bz * sB + (long)n0 * K;
  __shared__ __align__(16) u16 As[64 * 72];
  __shared__ __align__(16) u16 Bs[64 * 72];
  int tid = threadIdx.x;
  int lane = tid & 63, wave = tid >> 6;
  int wr = wave >> 1, wc = wave & 1;
  int kg = lane >> 4, r16 = lane & 15;
  f32x4 acc[2][2] = {};

  for (int k0 = 0; k0 < K; k0 += 64) {
    #pragma unroll
    for (int i = 0; i < 2; ++i) {
      int u = tid + i * 256;
      int row = u >> 3, seg = u & 7;
      *(u16x8*)(&As[row * 72 + seg * 8]) = *(const u16x8*)(Ab + (long)row * K + k0 + seg * 8);
      *(u16x8*)(&Bs[row * 72 + seg * 8]) = *(const u16x8*)(Bb + (long)row * K + k0 + seg * 8);
    }
    __syncthreads();
    #pragma unroll
    for (int kk = 0; kk < 2; ++kk) {
      s16x8 af[2], bfr[2];
      #pragma unroll
      for (int m = 0; m < 2; ++m)
        af[m] = *(const s16x8*)(&As[(wr * 32 + m * 16 + r16) * 72 + kk * 32 + kg * 8]);
      #pragma unroll
      for (int n = 0; n < 2; ++n)
        bfr[n] = *(const s16x8*)(&Bs[(wc * 32 + n * 16 + r16) * 72 + kk * 32 + kg * 8]);
      #pragma unroll
      for (int m = 0; m < 2; ++m)
        #pragma unroll
        for (int n = 0; n < 2; ++n)
          acc[m][n] = __builtin_amdgcn_mfma_f32_16x16x32_bf16(af[m], bfr[n], acc[m][n], 0, 0, 0);
    }
    __syncthreads();
  }

  #pragma unroll
  for (int m = 0; m < 2; ++m)
    #pragma unroll
    for (int r = 0; r < 4; ++r) {
      int row = m0 + wr * 32 + m * 16 + kg * 4 + r;
      #pragma unroll
      for (int n = 0; n < 2; ++n) {
        int col = n0 + wc * 32 + n * 16 + r16;
        long cidx = (long)bz * sC + (long)row * N + col;
        float v = acc[m][n][r];
        C[cidx] = v;
        if (Cbf) Cbf[cidx] = f2b(v);
      }
    }
}

// ---------------------------------------------------------------------------
// transpose-convert: X[b][R][C] f32 -> Y[b][C][R] bf16
// ---------------------------------------------------------------------------
__global__ __launch_bounds__(256) void k_convT(
    const float* __restrict__ X, u16* __restrict__ Y, int R, int C,
    long sX, long sY) {
  __shared__ float tile[32][33];
  const float* Xb = X + (long)blockIdx.z * sX;
  u16* Yb = Y + (long)blockIdx.z * sY;
  int tx = threadIdx.x & 31, ty = threadIdx.x >> 5;
  int r0 = blockIdx.y * 32, c0 = blockIdx.x * 32;
  #pragma unroll
  for (int i = 0; i < 4; ++i)
    tile[ty + i * 8][tx] = Xb[(long)(r0 + ty + i * 8) * C + (c0 + tx)];
  __syncthreads();
  #pragma unroll
  for (int i = 0; i < 4; ++i)
    Yb[(long)(c0 + ty + i * 8) * R + (r0 + tx)] = f2b(tile[tx][ty + i * 8]);
}

// cnt -> dis2
__global__ __launch_bounds__(256) void k_cnt2dis(
    const int* __restrict__ cnt, float* __restrict__ dis2, int n) {
  int i = blockIdx.x * 256 + threadIdx.x;
  if (i < n) dis2[i] = rsqrtf(1.0f + (float)cnt[i]);
}

// ---------------------------------------------------------------------------
// K4: t[row] = dot(x1[row,:], Watt)
// ---------------------------------------------------------------------------
__global__ __launch_bounds__(256) void k_att_dot(
    const float* __restrict__ x1, const float* __restrict__ Watt,
    float* __restrict__ t) {
  long row = blockIdx.x;
  float v = 0.f;
  if (threadIdx.x < H_) v = x1[row * H_ + threadIdx.x] * Watt[threadIdx.x];
  float s = blockReduceSum256(v);
  if (threadIdx.x == 0) t[row] = s;
}

// ---------------------------------------------------------------------------
// K5: alpha
// ---------------------------------------------------------------------------
__global__ __launch_bounds__(256) void k_alpha(
    const float* __restrict__ adj, const float* __restrict__ dis_bin,
    const float* __restrict__ t, const float* __restrict__ batt,
    float* __restrict__ alpha) {
  long row = blockIdx.x;
  int b = (int)(row >> 10), i = (int)(row & 1023);
  const float* a = adj + row * N_;
  const float* db = dis_bin + (long)b * N_;
  const float* tb = t + (long)b * N_;
  float s = 0.f;
  for (int j = threadIdx.x; j < N_; j += 256)
    if (a[j] != 0.0f) s += db[j] * tb[j];
  s = blockReduceSum256(s);
  if (threadIdx.x == 0) {
    float di = db[i];
    float pre = di * (s + di * tb[i]) + batt[0];
    float z = pre * pre;
    alpha[row] = 1.0f / (1.0f + expf(-z));
  }
}

// ---------------------------------------------------------------------------
// K6: per-batch stable descending sort, cut, index_mask, cut_alpha
// ---------------------------------------------------------------------------
__global__ __launch_bounds__(1024) void k_cutmask(
    const float* __restrict__ alpha, const int* __restrict__ num_sent,
    const int* __restrict__ nout, float* __restrict__ index_mask,
    float* __restrict__ ca) {
  int b = blockIdx.x, tid = threadIdx.x;
  __shared__ unsigned long long keys[N_];
  __shared__ int cs[N_];
  __shared__ int pos_s;
  float av = alpha[(long)b * N_ + tid];
  unsigned int bits = __float_as_uint(av);
  keys[tid] = ((unsigned long long)(0xFFFFFFFFu - bits) << 32) | (unsigned int)tid;
  __syncthreads();
  for (int kk = 2; kk <= N_; kk <<= 1) {
    for (int j = kk >> 1; j > 0; j >>= 1) {
      int ixj = tid ^ j;
      if (ixj > tid) {
        unsigned long long x = keys[tid], y = keys[ixj];
        bool up = ((tid & kk) == 0);
        if ((x > y) == up) { keys[tid] = y; keys[ixj] = x; }
      }
      __syncthreads();
    }
  }
  int ns = num_sent[b];
  int idx = (int)(keys[tid] & 0xFFFFFFFFull);
  cs[tid] = (idx < ns) ? 1 : 0;
  __syncthreads();
  for (int off = 1; off < N_; off <<= 1) {
    int add = (tid >= off) ? cs[tid - off] : 0;
    __syncthreads();
    cs[tid] += add;
    __syncthreads();
  }
  int k = nout[0];
  if (tid == 0) pos_s = 0;
  __syncthreads();
  if (cs[tid] >= k && (tid == 0 || cs[tid - 1] < k)) pos_s = tid;
  __syncthreads();
  float cut = __uint_as_float(0xFFFFFFFFu - (unsigned int)(keys[pos_s] >> 32));
  float myalpha = __uint_as_float(0xFFFFFFFFu - (unsigned int)(keys[tid] >> 32));
  index_mask[(long)b * N_ + idx] = (tid <= pos_s) ? 1.0f : 0.0f;
  ca[(long)b * N_ + idx] = fmaxf((myalpha + 1e-7f) - cut, 0.0f);
}

// ---------------------------------------------------------------------------
// K7: S build + L1 row-normalize + fused St bf16 transpose emission
// ---------------------------------------------------------------------------
__global__ __launch_bounds__(256) void k_build_S(
    const float* __restrict__ adj, const float* __restrict__ dr,
    const float* __restrict__ dc, const float* __restrict__ ca,
    float* __restrict__ S, u16* __restrict__ St) {
  long row = blockIdx.x;
  int b = (int)(row >> 10), i = (int)(row & 1023);
  const float* a = adj + row * N_;
  const float* dcb = dc + (long)b * N_;
  const float* cab = ca + (long)b * N_;
  float dri = dr[row];
  u16* StT = St + (long)b * (long)N_ * N_ + i;
  __shared__ float pre[N_];
  float ls = 0.f;
  for (int j = threadIdx.x; j < N_; j += 256) {
    float avv = a[j] + ((j == i) ? 1.0f : 0.0f);
    float v = dri * avv * dcb[j] * cab[j];
    pre[j] = v;
    ls += v;
  }
  float sum = blockReduceSum256(ls);
  float denom = fmaxf(sum, 1e-12f);
  for (int j = threadIdx.x; j < N_; j += 256) {
    float v = pre[j] / denom;
    S[row * N_ + j] = v;
    StT[(long)j * N_] = f2b(v);
  }
}

// ---------------------------------------------------------------------------
template<int W>
__global__ __launch_bounds__(256) void k_rowmean(
    const float* __restrict__ X, float* __restrict__ out) {
  long row = blockIdx.x;
  float s = 0.f;
  for (int j = threadIdx.x; j < W; j += 256) s += X[row * W + j];
  float r = blockReduceSum256(s);
  if (threadIdx.x == 0) out[row] = r / (float)W;
}

// ---------------------------------------------------------------------------
extern "C" void kernel_launch(void* const* d_in, const int* in_sizes, int n_in,
                              void* d_out, int out_size, void* d_ws, size_t ws_size,
                              hipStream_t stream) {
  const float* x     = (const float*)d_in[0];
  const float* adj   = (const float*)d_in[1];
  const int*   nsent = (const int*)d_in[2];
  const float* W1    = (const float*)d_in[3];
  const float* b1    = (const float*)d_in[4];
  const float* Watt  = (const float*)d_in[5];
  const float* batt  = (const float*)d_in[6];
  const float* W2    = (const float*)d_in[7];
  const float* b2    = (const float*)d_in[8];
  const int*   nout  = (const int*)d_in[9];

  const long NN = (long)N_ * N_;
  const long NH = (long)N_ * H_;
  const long NF = (long)N_ * F_;
  const int BN = B_ * N_;

  // output layout (flat concat, f32)
  float* out_x2   = (float*)d_out;
  float* out_cx   = out_x2 + (long)B_ * NF;
  float* out_cadj = out_cx + (long)B_ * NH;
  float* out_S    = out_cadj + (long)B_ * NN;
  float* out_im   = out_S + (long)B_ * NN;
  float* out_xs0  = out_im + BN;
  float* out_xs1  = out_xs0 + BN;

  // workspace (~140MB, proven scale)
  char* wsb = (char*)d_ws;
  float* P1      = (float*)wsb;
  float* x1      = P1 + (long)B_ * NH;
  float* t       = x1 + (long)B_ * NH;
  float* alpha   = t + BN;
  float* dis_bin = alpha + BN;
  float* dr      = dis_bin + BN;
  float* dc      = dr + BN;
  float* ca      = dc + BN;
  float* dis2    = ca + BN;
  int*   rowcnt  = (int*)(dis2 + BN);
  char*  p       = (char*)(rowcnt + BN);
  p = (char*)(((size_t)p + 255) & ~(size_t)255);
  u16* W1h   = (u16*)p;  p += (long)H_ * F_ * 2;
  u16* W1m   = (u16*)p;  p += (long)H_ * F_ * 2;
  u16* W1l   = (u16*)p;  p += (long)H_ * F_ * 2;
  u16* W2T   = (u16*)p;  p += (long)H_ * F_ * 2;
  u16* PT    = (u16*)p;  p += (long)B_ * NH * 2;   // x1T
  u16* St    = (u16*)p;  p += (long)B_ * NN * 2;   // xh -> St -> P2T
  u16* adjT  = (u16*)p;  p += (long)B_ * NN * 2;   // xm -> adjT -> cbin
  float* P2f = (float*)p;                           // xl -> P2f (50MB)
  u16* xh    = St;
  u16* xm    = adjT;
  u16* xl    = (u16*)P2f;
  u16* cx_bf = (u16*)P1;       // P1 dead after spmm; cx_bf written by G5 (after)
  u16* x1T   = PT;
  u16* cbin  = adjT;           // adjT dead after G6
  u16* P2T   = St;             // St dead after G7
  u16* StA   = (u16*)out_x2;   // scratch in unwritten output region

  // split x and W1 into 3 bf16 planes
  k_split3<<<dim3(2048), dim3(256), 0, stream>>>(x, xh, xm, xl, (long)B_ * NF / 4);
  k_convT3<<<dim3(H_ / 32, F_ / 32, 1), dim3(256), 0, stream>>>(W1, W1h, W1m, W1l);

  // zero rowcnt (used by G7 epilogue)
  hipMemsetAsync(rowcnt, 0, (size_t)BN * 4, stream);

  // G1: P1raw = x @ W1  (unscaled; dis applied in K2)
  mgemm64s3<<<dim3(H_ / 64, BN / 64, 1), dim3(256), 0, stream>>>(
      xh, xm, xl, W1h, W1m, W1l, P1, H_, F_);

  // K1: degrees + adjT emission (overwrites xm region, dead after G1)
  k_degrees<<<dim3(BN), dim3(256), 0, stream>>>(adj, dis_bin, dr, dc, adjT);

  // K2: x1 (dis applied here) + x1T emission
  k_spmm_relu<<<dim3(BN), dim3(256), 0, stream>>>(adj, P1, dis_bin, b1, x1, x1T);

  // attention + sort + S
  k_att_dot<<<dim3(BN), dim3(256), 0, stream>>>(x1, Watt, t);
  k_alpha<<<dim3(BN), dim3(256), 0, stream>>>(adj, dis_bin, t, batt, alpha);
  k_cutmask<<<dim3(B_), dim3(1024), 0, stream>>>(alpha, nsent, nout, out_im, ca);
  k_build_S<<<dim3(BN), dim3(256), 0, stream>>>(adj, dr, dc, ca, out_S, St);

  // G5: coarse_x = S^T @ x1 + fused cx_bf
  mgemm64<<<dim3(H_ / 64, N_ / 64, B_), dim3(256), 0, stream>>>(
      St, x1T, out_cx, H_, N_, NN, NH, NH, cx_bf);
  k_rowmean<H_><<<dim3(BN), dim3(256), 0, stream>>>(out_cx, out_xs0);

  // G6: StA = S^T @ adj (bf16 out)
  mgemm<1><<<dim3(N_ / 128, N_ / 128, B_), dim3(256), 0, stream>>>(
      St, adjT, StA, N_, N_, N_, NN, NN, NN, nullptr, nullptr, 0, nullptr,
      nullptr, nullptr);

  // G7: coarse_adj = floorq(StA @ S) + rowcnt + cbin (cbin -> old adjT region)
  mgemm<2><<<dim3(N_ / 128, N_ / 128, B_), dim3(256), 0, stream>>>(
      StA, St, out_cadj, N_, N_, N_, NN, NN, NN, nullptr, nullptr, 0, nullptr,
      rowcnt, cbin);

  // dis2 from fused counts
  k_cnt2dis<<<dim3((BN + 255) / 256), dim3(256), 0, stream>>>(rowcnt, dis2, BN);

  // W2T
  k_convT<<<dim3(F_ / 32, H_ / 32, 1), dim3(256), 0, stream>>>(W2, W2T, H_, F_, 0, 0);

  // G8: P2f = dis2 .* (coarse_x @ W2)
  mgemm<4><<<dim3(F_ / 128, BN / 128, 1), dim3(256), 0, stream>>>(
      cx_bf, W2T, P2f, BN, F_, H_, 0, 0, 0, dis2, nullptr, 0, nullptr,
      nullptr, nullptr);

  // P2T (-> old St region, dead after G7)
  k_convT<<<dim3(F_ / 32, N_ / 32, B_), dim3(256), 0, stream>>>(P2f, P2T, N_, F_, NF, NF);

  // G9: x2 = tanh(dis2_i*(cbin@P2 + P2_i) + b2)  (overwrites StA scratch)
  mgemm<3><<<dim3(F_ / 128, N_ / 128, B_), dim3(256), 0, stream>>>(
      cbin, P2T, out_x2, N_, F_, N_, NN, NF, NF, dis2, P2f, NF, b2,
      nullptr, nullptr);

  k_rowmean<F_><<<dim3(BN), dim3(256), 0, stream>>>(out_x2, out_xs1);
}

// Round 8
// 476.815 us; speedup vs baseline: 1.5011x; 1.5011x over previous
//
#include <hip/hip_runtime.h>

#define B_ 16
#define N_ 1024
#define F_ 768
#define H_ 128

typedef float f32x4 __attribute__((ext_vector_type(4)));
typedef short s16x8 __attribute__((ext_vector_type(8)));
typedef unsigned short u16;
typedef u16 u16x8 __attribute__((ext_vector_type(8)));
typedef u16 u16x4 __attribute__((ext_vector_type(4)));
typedef unsigned long long u64;

__device__ __forceinline__ u16 f2b(float f) {
  unsigned u = __float_as_uint(f);
  unsigned r = (u + 0x7FFFu + ((u >> 16) & 1u)) >> 16;
  return (u16)r;
}
__device__ __forceinline__ float b2f(u16 u) {
  return __uint_as_float(((unsigned)u) << 16);
}

__device__ __forceinline__ void gload16(const u16* g, u16* l) {
  __builtin_amdgcn_global_load_lds(
      (const __attribute__((address_space(1))) unsigned int*)g,
      (__attribute__((address_space(3))) unsigned int*)l, 16, 0, 0);
}

// ---------------------------------------------------------------------------
__device__ __forceinline__ float blockReduceSum256(float v) {
  __shared__ float red[4];
  #pragma unroll
  for (int o = 32; o > 0; o >>= 1) v += __shfl_down(v, o, 64);
  if ((threadIdx.x & 63) == 0) red[threadIdx.x >> 6] = v;
  __syncthreads();
  float r = red[0] + red[1] + red[2] + red[3];
  __syncthreads();
  return r;
}

// ---------------------------------------------------------------------------
// K1: degrees + adjacency bitmask emission (ballot; 16 u64 words per row)
// ---------------------------------------------------------------------------
__global__ __launch_bounds__(256) void k_degrees(
    const float* __restrict__ adj, float* __restrict__ dis_bin,
    float* __restrict__ dr, float* __restrict__ dc, u64* __restrict__ bm) {
  long row = blockIdx.x;
  const float* a = adj + row * N_;
  int tid = threadIdx.x;
  float cnt = 0.f, sw = 0.f;
  #pragma unroll
  for (int it = 0; it < 4; ++it) {
    int j = tid + it * 256;
    float v = a[j];
    bool nz = (v != 0.0f);
    u64 ball = __ballot(nz);
    if ((tid & 63) == 0) bm[row * 16 + it * 4 + (tid >> 6)] = ball;
    if (nz) { cnt += 1.0f; sw += v; }
  }
  __shared__ float r1[4], r2[4];
  #pragma unroll
  for (int o = 32; o > 0; o >>= 1) { cnt += __shfl_down(cnt, o, 64); sw += __shfl_down(sw, o, 64); }
  if ((tid & 63) == 0) { r1[tid >> 6] = cnt; r2[tid >> 6] = sw; }
  __syncthreads();
  if (tid == 0) {
    float c = r1[0] + r1[1] + r1[2] + r1[3];
    float s = r2[0] + r2[1] + r2[2] + r2[3];
    dis_bin[row] = rsqrtf(c + 1.0f);
    float d = rsqrtf(s + 1.0f);
    dc[row] = d;
    dr[row] = (s > 0.0f) ? d : 0.0f;
  }
}

// ---------------------------------------------------------------------------
// split f32 -> 3 bf16 planes
// ---------------------------------------------------------------------------
__global__ __launch_bounds__(256) void k_split3(
    const float* __restrict__ X, u16* __restrict__ Yh, u16* __restrict__ Ym,
    u16* __restrict__ Yl, long n4) {
  long i = (long)blockIdx.x * 256 + threadIdx.x;
  long stride = (long)gridDim.x * 256;
  for (; i < n4; i += stride) {
    f32x4 v = *(const f32x4*)(X + i * 4);
    u16x4 oh, om, ol;
    #pragma unroll
    for (int e = 0; e < 4; ++e) {
      float f = v[e];
      u16 h = f2b(f); float r1 = f - b2f(h);
      u16 m = f2b(r1); float r2 = r1 - b2f(m);
      u16 l = f2b(r2);
      oh[e] = h; om[e] = m; ol[e] = l;
    }
    *(u16x4*)(Yh + i * 4) = oh;
    *(u16x4*)(Ym + i * 4) = om;
    *(u16x4*)(Yl + i * 4) = ol;
  }
}

// transpose W1 [F][H] -> [H][F] with 3-way split
__global__ __launch_bounds__(256) void k_convT3(
    const float* __restrict__ X, u16* __restrict__ Yh, u16* __restrict__ Ym,
    u16* __restrict__ Yl) {
  __shared__ float tile[32][33];
  int tx = threadIdx.x & 31, ty = threadIdx.x >> 5;
  int r0 = blockIdx.y * 32, c0 = blockIdx.x * 32;
  #pragma unroll
  for (int i = 0; i < 4; ++i)
    tile[ty + i * 8][tx] = X[(long)(r0 + ty + i * 8) * H_ + (c0 + tx)];
  __syncthreads();
  #pragma unroll
  for (int i = 0; i < 4; ++i) {
    float v = tile[tx][ty + i * 8];
    long o = (long)(c0 + ty + i * 8) * F_ + (r0 + tx);
    u16 h = f2b(v); float r1 = v - b2f(h);
    u16 m = f2b(r1); float r2 = r1 - b2f(m);
    u16 l = f2b(r2);
    Yh[o] = h; Ym[o] = m; Yl[o] = l;
  }
}

// ---------------------------------------------------------------------------
// G1: P1raw = (A0+A1+A2) @ (B0+B1+B2)^T  (6-product split-3 MFMA)
// ---------------------------------------------------------------------------
__global__ __launch_bounds__(256) void mgemm64s3(
    const u16* __restrict__ A0, const u16* __restrict__ A1, const u16* __restrict__ A2,
    const u16* __restrict__ B0, const u16* __restrict__ B1, const u16* __restrict__ B2,
    float* __restrict__ C, int N, int K) {
  int m0 = blockIdx.y * 64, n0 = blockIdx.x * 64;
  __shared__ __align__(16) u16 As[3][64 * 72];
  __shared__ __align__(16) u16 Bs[3][64 * 72];
  const u16* Ap[3] = {A0 + (long)m0 * K, A1 + (long)m0 * K, A2 + (long)m0 * K};
  const u16* Bp[3] = {B0 + (long)n0 * K, B1 + (long)n0 * K, B2 + (long)n0 * K};
  int tid = threadIdx.x, lane = tid & 63, wave = tid >> 6;
  int wr = wave >> 1, wc = wave & 1, kg = lane >> 4, r16 = lane & 15;
  f32x4 acc[2][2] = {};

  for (int k0 = 0; k0 < K; k0 += 64) {
    #pragma unroll
    for (int t = 0; t < 3; ++t) {
      #pragma unroll
      for (int i = 0; i < 2; ++i) {
        int u = tid + i * 256;
        int row = u >> 3, seg = u & 7;
        *(u16x8*)(&As[t][row * 72 + seg * 8]) = *(const u16x8*)(Ap[t] + (long)row * K + k0 + seg * 8);
        *(u16x8*)(&Bs[t][row * 72 + seg * 8]) = *(const u16x8*)(Bp[t] + (long)row * K + k0 + seg * 8);
      }
    }
    __syncthreads();
    #pragma unroll
    for (int kk = 0; kk < 2; ++kk) {
      s16x8 ah[2], am[2], al[2], bh[2], bm2[2], bl[2];
      #pragma unroll
      for (int m = 0; m < 2; ++m) {
        int off = (wr * 32 + m * 16 + r16) * 72 + kk * 32 + kg * 8;
        ah[m] = *(const s16x8*)(&As[0][off]);
        am[m] = *(const s16x8*)(&As[1][off]);
        al[m] = *(const s16x8*)(&As[2][off]);
      }
      #pragma unroll
      for (int n = 0; n < 2; ++n) {
        int off = (wc * 32 + n * 16 + r16) * 72 + kk * 32 + kg * 8;
        bh[n] = *(const s16x8*)(&Bs[0][off]);
        bm2[n] = *(const s16x8*)(&Bs[1][off]);
        bl[n] = *(const s16x8*)(&Bs[2][off]);
      }
      #pragma unroll
      for (int m = 0; m < 2; ++m)
        #pragma unroll
        for (int n = 0; n < 2; ++n) {
          acc[m][n] = __builtin_amdgcn_mfma_f32_16x16x32_bf16(ah[m], bh[n], acc[m][n], 0, 0, 0);
          acc[m][n] = __builtin_amdgcn_mfma_f32_16x16x32_bf16(ah[m], bm2[n], acc[m][n], 0, 0, 0);
          acc[m][n] = __builtin_amdgcn_mfma_f32_16x16x32_bf16(am[m], bh[n], acc[m][n], 0, 0, 0);
          acc[m][n] = __builtin_amdgcn_mfma_f32_16x16x32_bf16(am[m], bm2[n], acc[m][n], 0, 0, 0);
          acc[m][n] = __builtin_amdgcn_mfma_f32_16x16x32_bf16(ah[m], bl[n], acc[m][n], 0, 0, 0);
          acc[m][n] = __builtin_amdgcn_mfma_f32_16x16x32_bf16(al[m], bh[n], acc[m][n], 0, 0, 0);
        }
    }
    __syncthreads();
  }

  #pragma unroll
  for (int m = 0; m < 2; ++m)
    #pragma unroll
    for (int r = 0; r < 4; ++r) {
      int row = m0 + wr * 32 + m * 16 + kg * 4 + r;
      #pragma unroll
      for (int n = 0; n < 2; ++n) {
        int col = n0 + wc * 32 + n * 16 + r16;
        C[(long)row * N + col] = acc[m][n][r];
      }
    }
}

// ---------------------------------------------------------------------------
// K2: x1 = relu(dis_i*(sum_{bit j} dis_j*P1_j + dis_i*P1_i) + b1)
// bitmask-driven; fused t[row] = x1_row . Watt
// ---------------------------------------------------------------------------
__global__ __launch_bounds__(256) void k_spmm_relu(
    const u64* __restrict__ bm, const float* __restrict__ P1,
    const float* __restrict__ dis_bin, const float* __restrict__ b1,
    const float* __restrict__ Watt, float* __restrict__ x1,
    float* __restrict__ t) {
  long row = blockIdx.x;
  int b = (int)(row >> 10), i = (int)(row & 1023);
  const float* Pb = P1 + (long)b * (long)N_ * H_;
  const float* db = dis_bin + (long)b * N_;
  __shared__ int idxs[N_];
  __shared__ int tcnt[256];
  __shared__ float accs[H_];
  int tid = threadIdx.x;
  int base = tid * 4;
  u64 word = bm[row * 16 + (tid >> 4)];
  int sh = base & 63;
  int f0 = (int)((word >> sh) & 1), f1 = (int)((word >> (sh + 1)) & 1);
  int f2 = (int)((word >> (sh + 2)) & 1), f3 = (int)((word >> (sh + 3)) & 1);
  int c0 = f0 + f1 + f2 + f3;
  tcnt[tid] = c0;
  __syncthreads();
  for (int off = 1; off < 256; off <<= 1) {
    int add = (tid >= off) ? tcnt[tid - off] : 0;
    __syncthreads();
    tcnt[tid] += add;
    __syncthreads();
  }
  int pos = tcnt[tid] - c0;
  int n = tcnt[255];
  if (f0) idxs[pos++] = base;
  if (f1) idxs[pos++] = base + 1;
  if (f2) idxs[pos++] = base + 2;
  if (f3) idxs[pos++] = base + 3;
  __syncthreads();
  int c = tid & 127, team = tid >> 7;
  float acc = 0.f;
  for (int u = team; u < n; u += 2) {
    int j = idxs[u];
    acc += db[j] * Pb[(long)j * H_ + c];
  }
  if (team == 1) accs[c] = acc;
  __syncthreads();
  float v = 0.f;
  if (team == 0) {
    float di = db[i];
    float tot = acc + accs[c] + di * Pb[(long)i * H_ + c];
    v = fmaxf(di * tot + b1[c], 0.0f);
    x1[row * H_ + c] = v;
  }
  __syncthreads();
  float prod = (team == 0) ? v * Watt[c] : 0.f;
  float s = blockReduceSum256(prod);
  if (tid == 0) t[row] = s;
}

// ---------------------------------------------------------------------------
// K5: alpha (bitmask-driven)
// ---------------------------------------------------------------------------
__global__ __launch_bounds__(256) void k_alpha(
    const u64* __restrict__ bm, const float* __restrict__ dis_bin,
    const float* __restrict__ t, const float* __restrict__ batt,
    float* __restrict__ alpha) {
  long row = blockIdx.x;
  int b = (int)(row >> 10), i = (int)(row & 1023);
  const float* db = dis_bin + (long)b * N_;
  const float* tb = t + (long)b * N_;
  int tid = threadIdx.x;
  float s = 0.f;
  #pragma unroll
  for (int it = 0; it < 4; ++it) {
    int j = tid + it * 256;
    u64 word = bm[row * 16 + (j >> 6)];
    if ((word >> (j & 63)) & 1) s += db[j] * tb[j];
  }
  s = blockReduceSum256(s);
  if (tid == 0) {
    float di = db[i];
    float pre = di * (s + di * tb[i]) + batt[0];
    float z = pre * pre;
    alpha[row] = 1.0f / (1.0f + expf(-z));
  }
}

// ---------------------------------------------------------------------------
// K6: top-k cut + mask (replaces bitonic sort; exact stable-sort semantics
// via composite key (bits(alpha)<<32)|(~idx): mask[i] = key_i >= key_cut)
// ---------------------------------------------------------------------------
__global__ __launch_bounds__(1024) void k_cutmask2(
    const float* __restrict__ alpha, const int* __restrict__ num_sent,
    const int* __restrict__ nout, float* __restrict__ index_mask,
    float* __restrict__ ca) {
  int b = blockIdx.x, tid = threadIdx.x;
  __shared__ u64 keys[N_];
  __shared__ u64 red[N_];
  int ns = num_sent[b];
  float av = alpha[(long)b * N_ + tid];
  unsigned bits = __float_as_uint(av);
  u64 keyFull = ((u64)bits << 32) | (u64)(0xFFFFFFFFu - (unsigned)tid);
  keys[tid] = (tid < ns) ? keyFull : 0ULL;
  __syncthreads();
  int k = nout[0];
  u64 cutkey = 0;
  for (int r = 0; r < k; ++r) {
    red[tid] = keys[tid];
    __syncthreads();
    for (int off = 512; off > 0; off >>= 1) {
      if (tid < off) { u64 o = red[tid + off]; if (o > red[tid]) red[tid] = o; }
      __syncthreads();
    }
    u64 mx = red[0];
    __syncthreads();
    if (r == k - 1) cutkey = mx;
    else if (keys[tid] == mx) keys[tid] = 0ULL;
    __syncthreads();
  }
  float cutalpha = __uint_as_float((unsigned)(cutkey >> 32));
  index_mask[(long)b * N_ + tid] = (keyFull >= cutkey) ? 1.0f : 0.0f;
  ca[(long)b * N_ + tid] = fmaxf(av + 1e-7f - cutalpha, 0.0f);
}

// ---------------------------------------------------------------------------
// K7: S build + L1 row-normalize (coalesced f32 out only)
// ---------------------------------------------------------------------------
__global__ __launch_bounds__(256) void k_build_S(
    const float* __restrict__ adj, const float* __restrict__ dr,
    const float* __restrict__ dc, const float* __restrict__ ca,
    float* __restrict__ S) {
  long row = blockIdx.x;
  int b = (int)(row >> 10), i = (int)(row & 1023);
  const float* a = adj + row * N_;
  const float* dcb = dc + (long)b * N_;
  const float* cab = ca + (long)b * N_;
  float dri = dr[row];
  __shared__ float pre[N_];
  float ls = 0.f;
  for (int j = threadIdx.x; j < N_; j += 256) {
    float avv = a[j] + ((j == i) ? 1.0f : 0.0f);
    float v = dri * avv * dcb[j] * cab[j];
    pre[j] = v;
    ls += v;
  }
  float sum = blockReduceSum256(ls);
  float denom = fmaxf(sum, 1e-12f);
  for (int j = threadIdx.x; j < N_; j += 256)
    S[row * N_ + j] = pre[j] / denom;
}

// ---------------------------------------------------------------------------
// Big MFMA GEMM: 128x128 tile, BK=32, global_load_lds staging, XCD swizzle.
// MODE 1: bf16 C | 2: floorq + rowcnt + cbin(diag+1) | 3: tanh(sc*acc+bias) |
// 4: scale[row]*acc
// ---------------------------------------------------------------------------
template<int MODE>
__global__ __launch_bounds__(256) void mgemm(
    const u16* __restrict__ A, const u16* __restrict__ Bt, void* __restrict__ Cv,
    int M, int N, int K, long sA, long sB, long sC,
    const float* __restrict__ scale, const float* __restrict__ bias,
    int* __restrict__ rowcnt, u16* __restrict__ cbin) {
  // XCD-aware bijective chunked remap (total blocks divisible by 8)
  int gx = gridDim.x, gy = gridDim.y;
  int lin = (blockIdx.z * gy + blockIdx.y) * gx + blockIdx.x;
  int total = gx * gy * gridDim.z;
  int chunk = total >> 3;
  int swz = (lin & 7) * chunk + (lin >> 3);
  int bx = swz % gx; int t2 = swz / gx; int by = t2 % gy; int bz = t2 / gy;

  int m0 = by * 128, n0 = bx * 128;
  const u16* Ab = A + (long)bz * sA + (long)m0 * K;
  const u16* Bb = Bt + (long)bz * sB + (long)n0 * K;
  __shared__ __align__(16) u16 As[128 * 32];
  __shared__ __align__(16) u16 Bs[128 * 32];
  int tid = threadIdx.x;
  int lane = tid & 63, wave = tid >> 6;
  int wr = wave >> 1, wc = wave & 1;
  int kg = lane >> 4, r16 = lane & 15;
  const u16* ga = Ab + (long)(tid >> 2) * K + (tid & 3) * 8;
  const u16* gb = Bb + (long)(tid >> 2) * K + (tid & 3) * 8;
  f32x4 acc[4][4] = {};

  for (int k0 = 0; k0 < K; k0 += 32) {
    gload16(ga + k0, &As[tid * 8]);
    gload16(ga + (long)64 * K + k0, &As[2048 + tid * 8]);
    gload16(gb + k0, &Bs[tid * 8]);
    gload16(gb + (long)64 * K + k0, &Bs[2048 + tid * 8]);
    __syncthreads();
    s16x8 af[4], bfr[4];
    #pragma unroll
    for (int m = 0; m < 4; ++m)
      af[m] = *(const s16x8*)(&As[(wr * 64 + m * 16 + r16) * 32 + kg * 8]);
    #pragma unroll
    for (int n = 0; n < 4; ++n)
      bfr[n] = *(const s16x8*)(&Bs[(wc * 64 + n * 16 + r16) * 32 + kg * 8]);
    #pragma unroll
    for (int m = 0; m < 4; ++m)
      #pragma unroll
      for (int n = 0; n < 4; ++n)
        acc[m][n] = __builtin_amdgcn_mfma_f32_16x16x32_bf16(af[m], bfr[n], acc[m][n], 0, 0, 0);
    __syncthreads();
  }

  if constexpr (MODE == 2) {
    int* cnt = (int*)As;
    if (tid < 128) cnt[tid] = 0;
    __syncthreads();
    #pragma unroll
    for (int m = 0; m < 4; ++m) {
      #pragma unroll
      for (int r = 0; r < 4; ++r) {
        int lrow = wr * 64 + m * 16 + kg * 4 + r;
        int row = m0 + lrow;
        int nz = 0;
        #pragma unroll
        for (int n = 0; n < 4; ++n) {
          int col = n0 + wc * 64 + n * 16 + r16;
          float q = floorf(acc[m][n][r] * 10000.0f) / 10000.0f;
          long cidx = (long)bz * sC + (long)row * N + col;
          ((float*)Cv)[cidx] = q;
          bool qnz = (q != 0.0f);
          u16 bv;
          if (row == col) bv = qnz ? (u16)0x4000 : (u16)0x3F80;  // bin+I diag
          else            bv = qnz ? (u16)0x3F80 : (u16)0;
          cbin[cidx] = bv;
          nz += qnz ? 1 : 0;
        }
        atomicAdd(&cnt[lrow], nz);
      }
    }
    __syncthreads();
    if (tid < 128) atomicAdd(&rowcnt[(long)bz * N_ + m0 + tid], cnt[tid]);
    return;
  }

  #pragma unroll
  for (int m = 0; m < 4; ++m) {
    #pragma unroll
    for (int r = 0; r < 4; ++r) {
      int row = m0 + wr * 64 + m * 16 + kg * 4 + r;
      float sc = 0.f;
      if constexpr (MODE == 3) sc = scale[(long)bz * N_ + row];
      if constexpr (MODE == 4) sc = scale[row];
      #pragma unroll
      for (int n = 0; n < 4; ++n) {
        int col = n0 + wc * 64 + n * 16 + r16;
        float v = acc[m][n][r];
        long cidx = (long)bz * sC + (long)row * N + col;
        if constexpr (MODE == 1) {
          ((u16*)Cv)[cidx] = f2b(v);
        } else if constexpr (MODE == 3) {
          ((float*)Cv)[cidx] = tanhf(sc * v + bias[col]);
        } else if constexpr (MODE == 4) {
          ((float*)Cv)[cidx] = sc * v;
        } else {
          ((float*)Cv)[cidx] = v;
        }
      }
    }
  }
}

// ---------------------------------------------------------------------------
// Small-N MFMA GEMM: 64x64 tile, BK=64, reg-staged, pad-72 LDS.
// f32 C + optional bf16 mirror.
// ---------------------------------------------------------------------------
__global__ __launch_bounds__(256) void mgemm64(
    const u16* __restrict__ A, const u16* __restrict__ Bt, float* __restrict__ C,
    int N, int K, long sA, long sB, long sC, u16* __restrict__ Cbf) {
  int bz = blockIdx.z;
  int m0 = blockIdx.y * 64, n0 = blockIdx.x * 64;
  const u16* Ab = A + (long)bz * sA + (long)m0 * K;
  const u16* Bb = Bt + (long)bz * sB + (long)n0 * K;
  __shared__ __align__(16) u16 As[64 * 72];
  __shared__ __align__(16) u16 Bs[64 * 72];
  int tid = threadIdx.x;
  int lane = tid & 63, wave = tid >> 6;
  int wr = wave >> 1, wc = wave & 1;
  int kg = lane >> 4, r16 = lane & 15;
  f32x4 acc[2][2] = {};

  for (int k0 = 0; k0 < K; k0 += 64) {
    #pragma unroll
    for (int i = 0; i < 2; ++i) {
      int u = tid + i * 256;
      int row = u >> 3, seg = u & 7;
      *(u16x8*)(&As[row * 72 + seg * 8]) = *(const u16x8*)(Ab + (long)row * K + k0 + seg * 8);
      *(u16x8*)(&Bs[row * 72 + seg * 8]) = *(const u16x8*)(Bb + (long)row * K + k0 + seg * 8);
    }
    __syncthreads();
    #pragma unroll
    for (int kk = 0; kk < 2; ++kk) {
      s16x8 af[2], bfr[2];
      #pragma unroll
      for (int m = 0; m < 2; ++m)
        af[m] = *(const s16x8*)(&As[(wr * 32 + m * 16 + r16) * 72 + kk * 32 + kg * 8]);
      #pragma unroll
      for (int n = 0; n < 2; ++n)
        bfr[n] = *(const s16x8*)(&Bs[(wc * 32 + n * 16 + r16) * 72 + kk * 32 + kg * 8]);
      #pragma unroll
      for (int m = 0; m < 2; ++m)
        #pragma unroll
        for (int n = 0; n < 2; ++n)
          acc[m][n] = __builtin_amdgcn_mfma_f32_16x16x32_bf16(af[m], bfr[n], acc[m][n], 0, 0, 0);
    }
    __syncthreads();
  }

  #pragma unroll
  for (int m = 0; m < 2; ++m)
    #pragma unroll
    for (int r = 0; r < 4; ++r) {
      int row = m0 + wr * 32 + m * 16 + kg * 4 + r;
      #pragma unroll
      for (int n = 0; n < 2; ++n) {
        int col = n0 + wc * 32 + n * 16 + r16;
        long cidx = (long)bz * sC + (long)row * N + col;
        float v = acc[m][n][r];
        C[cidx] = v;
        if (Cbf) Cbf[cidx] = f2b(v);
      }
    }
}

// ---------------------------------------------------------------------------
// transpose-convert: X[b][R][C] f32 -> Y[b][C][R] bf16 (LDS-staged, coalesced)
// ---------------------------------------------------------------------------
__global__ __launch_bounds__(256) void k_convT(
    const float* __restrict__ X, u16* __restrict__ Y, int R, int C,
    long sX, long sY) {
  __shared__ float tile[32][33];
  const float* Xb = X + (long)blockIdx.z * sX;
  u16* Yb = Y + (long)blockIdx.z * sY;
  int tx = threadIdx.x & 31, ty = threadIdx.x >> 5;
  int r0 = blockIdx.y * 32, c0 = blockIdx.x * 32;
  #pragma unroll
  for (int i = 0; i < 4; ++i)
    tile[ty + i * 8][tx] = Xb[(long)(r0 + ty + i * 8) * C + (c0 + tx)];
  __syncthreads();
  #pragma unroll
  for (int i = 0; i < 4; ++i)
    Yb[(long)(c0 + ty + i * 8) * R + (r0 + tx)] = f2b(tile[tx][ty + i * 8]);
}

// cnt -> dis2
__global__ __launch_bounds__(256) void k_cnt2dis(
    const int* __restrict__ cnt, float* __restrict__ dis2, int n) {
  int i = blockIdx.x * 256 + threadIdx.x;
  if (i < n) dis2[i] = rsqrtf(1.0f + (float)cnt[i]);
}

// ---------------------------------------------------------------------------
template<int W>
__global__ __launch_bounds__(256) void k_rowmean(
    const float* __restrict__ X, float* __restrict__ out) {
  long row = blockIdx.x;
  float s = 0.f;
  for (int j = threadIdx.x; j < W; j += 256) s += X[row * W + j];
  float r = blockReduceSum256(s);
  if (threadIdx.x == 0) out[row] = r / (float)W;
}

// ---------------------------------------------------------------------------
extern "C" void kernel_launch(void* const* d_in, const int* in_sizes, int n_in,
                              void* d_out, int out_size, void* d_ws, size_t ws_size,
                              hipStream_t stream) {
  const float* x     = (const float*)d_in[0];
  const float* adj   = (const float*)d_in[1];
  const int*   nsent = (const int*)d_in[2];
  const float* W1    = (const float*)d_in[3];
  const float* b1    = (const float*)d_in[4];
  const float* Watt  = (const float*)d_in[5];
  const float* batt  = (const float*)d_in[6];
  const float* W2    = (const float*)d_in[7];
  const float* b2    = (const float*)d_in[8];
  const int*   nout  = (const int*)d_in[9];

  const long NN = (long)N_ * N_;
  const long NH = (long)N_ * H_;
  const long NF = (long)N_ * F_;
  const int BN = B_ * N_;

  // output layout (flat concat, f32)
  float* out_x2   = (float*)d_out;
  float* out_cx   = out_x2 + (long)B_ * NF;
  float* out_cadj = out_cx + (long)B_ * NH;
  float* out_S    = out_cadj + (long)B_ * NN;
  float* out_im   = out_S + (long)B_ * NN;
  float* out_xs0  = out_im + BN;
  float* out_xs1  = out_xs0 + BN;

  // workspace (~142MB, proven scale)
  char* wsb = (char*)d_ws;
  float* P1      = (float*)wsb;
  float* x1      = P1 + (long)B_ * NH;
  float* t       = x1 + (long)B_ * NH;
  float* alpha   = t + BN;
  float* dis_bin = alpha + BN;
  float* dr      = dis_bin + BN;
  float* dc      = dr + BN;
  float* ca      = dc + BN;
  float* dis2    = ca + BN;
  int*   rowcnt  = (int*)(dis2 + BN);
  u64*   bm      = (u64*)(rowcnt + BN);       // 2MB bitmask
  char*  p       = (char*)(bm + (long)BN * 16);
  p = (char*)(((size_t)p + 255) & ~(size_t)255);
  u16* W1h   = (u16*)p;  p += (long)H_ * F_ * 2;
  u16* W1m   = (u16*)p;  p += (long)H_ * F_ * 2;
  u16* W1l   = (u16*)p;  p += (long)H_ * F_ * 2;
  u16* W2T   = (u16*)p;  p += (long)H_ * F_ * 2;
  u16* PT    = (u16*)p;  p += (long)B_ * NH * 2;   // x1T
  u16* St    = (u16*)p;  p += (long)B_ * NN * 2;   // xh -> St -> P2T
  u16* adjT  = (u16*)p;  p += (long)B_ * NN * 2;   // xm -> adjT -> cbin
  float* P2f = (float*)p;                           // xl -> P2f (50MB)
  u16* xh    = St;
  u16* xm    = adjT;
  u16* xl    = (u16*)P2f;
  u16* cx_bf = (u16*)P1;       // P1 dead after spmm
  u16* x1T   = PT;
  u16* cbin  = adjT;           // adjT dead after G6
  u16* P2T   = St;             // St dead after G7
  u16* StA   = (u16*)out_x2;   // scratch in unwritten output region

  // split x and W1 into 3 bf16 planes
  k_split3<<<dim3(2048), dim3(256), 0, stream>>>(x, xh, xm, xl, (long)B_ * NF / 4);
  k_convT3<<<dim3(H_ / 32, F_ / 32, 1), dim3(256), 0, stream>>>(W1, W1h, W1m, W1l);

  hipMemsetAsync(rowcnt, 0, (size_t)BN * 4, stream);

  // G1: P1raw = x @ W1  (split-3 MFMA; dis applied in K2)
  mgemm64s3<<<dim3(H_ / 64, BN / 64, 1), dim3(256), 0, stream>>>(
      xh, xm, xl, W1h, W1m, W1l, P1, H_, F_);

  // K1: degrees + bitmask
  k_degrees<<<dim3(BN), dim3(256), 0, stream>>>(adj, dis_bin, dr, dc, bm);

  // K2: x1 + fused t (bitmask)
  k_spmm_relu<<<dim3(BN), dim3(256), 0, stream>>>(bm, P1, dis_bin, b1, Watt, x1, t);

  // alpha + top-k cut/mask + S
  k_alpha<<<dim3(BN), dim3(256), 0, stream>>>(bm, dis_bin, t, batt, alpha);
  k_cutmask2<<<dim3(B_), dim3(1024), 0, stream>>>(alpha, nsent, nout, out_im, ca);
  k_build_S<<<dim3(BN), dim3(256), 0, stream>>>(adj, dr, dc, ca, out_S);

  // transposes (LDS-staged, coalesced): St, x1T, adjT
  k_convT<<<dim3(N_ / 32, N_ / 32, B_), dim3(256), 0, stream>>>(out_S, St, N_, N_, NN, NN);
  k_convT<<<dim3(H_ / 32, N_ / 32, B_), dim3(256), 0, stream>>>(x1, x1T, N_, H_, NH, NH);
  k_convT<<<dim3(N_ / 32, N_ / 32, B_), dim3(256), 0, stream>>>(adj, adjT, N_, N_, NN, NN);

  // G5: coarse_x = S^T @ x1 + fused cx_bf
  mgemm64<<<dim3(H_ / 64, N_ / 64, B_), dim3(256), 0, stream>>>(
      St, x1T, out_cx, H_, N_, NN, NH, NH, cx_bf);
  k_rowmean<H_><<<dim3(BN), dim3(256), 0, stream>>>(out_cx, out_xs0);

  // G6: StA = S^T @ adj (bf16 out)
  mgemm<1><<<dim3(N_ / 128, N_ / 128, B_), dim3(256), 0, stream>>>(
      St, adjT, StA, N_, N_, N_, NN, NN, NN, nullptr, nullptr, nullptr, nullptr);

  // G7: coarse_adj = floorq(StA @ S) + rowcnt + cbin(diag+1) (-> adjT region)
  mgemm<2><<<dim3(N_ / 128, N_ / 128, B_), dim3(256), 0, stream>>>(
      StA, St, out_cadj, N_, N_, N_, NN, NN, NN, nullptr, nullptr, rowcnt, cbin);

  k_cnt2dis<<<dim3((BN + 255) / 256), dim3(256), 0, stream>>>(rowcnt, dis2, BN);

  // W2T
  k_convT<<<dim3(F_ / 32, H_ / 32, 1), dim3(256), 0, stream>>>(W2, W2T, H_, F_, 0, 0);

  // G8: P2f = dis2 .* (coarse_x @ W2)
  mgemm<4><<<dim3(F_ / 128, BN / 128, 1), dim3(256), 0, stream>>>(
      cx_bf, W2T, P2f, BN, F_, H_, 0, 0, 0, dis2, nullptr, nullptr, nullptr);

  // P2T (-> St region, dead after G7)
  k_convT<<<dim3(F_ / 32, N_ / 32, B_), dim3(256), 0, stream>>>(P2f, P2T, N_, F_, NF, NF);

  // G9: x2 = tanh(dis2_i * (cbin' @ P2) + b2)   (diag folded; no Add read)
  mgemm<3><<<dim3(F_ / 128, N_ / 128, B_), dim3(256), 0, stream>>>(
      cbin, P2T, out_x2, N_, F_, N_, NN, NF, NF, dis2, b2, nullptr, nullptr);

  k_rowmean<F_><<<dim3(BN), dim3(256), 0, stream>>>(out_x2, out_xs1);
}

// Round 9
// 464.428 us; speedup vs baseline: 1.5412x; 1.0267x over previous
//
#include <hip/hip_runtime.h>

#define B_ 16
#define N_ 1024
#define F_ 768
#define H_ 128

typedef float f32x4 __attribute__((ext_vector_type(4)));
typedef short s16x8 __attribute__((ext_vector_type(8)));
typedef unsigned short u16;
typedef u16 u16x8 __attribute__((ext_vector_type(8)));
typedef u16 u16x4 __attribute__((ext_vector_type(4)));
typedef unsigned long long u64;

__device__ __forceinline__ u16 f2b(float f) {
  unsigned u = __float_as_uint(f);
  unsigned r = (u + 0x7FFFu + ((u >> 16) & 1u)) >> 16;
  return (u16)r;
}
__device__ __forceinline__ float b2f(u16 u) {
  return __uint_as_float(((unsigned)u) << 16);
}

__device__ __forceinline__ void gload16(const u16* g, u16* l) {
  __builtin_amdgcn_global_load_lds(
      (const __attribute__((address_space(1))) unsigned int*)g,
      (__attribute__((address_space(3))) unsigned int*)l, 16, 0, 0);
}

// ---------------------------------------------------------------------------
__device__ __forceinline__ float blockReduceSum256(float v) {
  __shared__ float red[4];
  #pragma unroll
  for (int o = 32; o > 0; o >>= 1) v += __shfl_down(v, o, 64);
  if ((threadIdx.x & 63) == 0) red[threadIdx.x >> 6] = v;
  __syncthreads();
  float r = red[0] + red[1] + red[2] + red[3];
  __syncthreads();
  return r;
}

// ---------------------------------------------------------------------------
// K1: degrees + adjacency bitmask emission (ballot; 16 u64 words per row)
// ---------------------------------------------------------------------------
__global__ __launch_bounds__(256) void k_degrees(
    const float* __restrict__ adj, float* __restrict__ dis_bin,
    float* __restrict__ dr, float* __restrict__ dc, u64* __restrict__ bm) {
  long row = blockIdx.x;
  const float* a = adj + row * N_;
  int tid = threadIdx.x;
  float cnt = 0.f, sw = 0.f;
  #pragma unroll
  for (int it = 0; it < 4; ++it) {
    int j = tid + it * 256;
    float v = a[j];
    bool nz = (v != 0.0f);
    u64 ball = __ballot(nz);
    if ((tid & 63) == 0) bm[row * 16 + it * 4 + (tid >> 6)] = ball;
    if (nz) { cnt += 1.0f; sw += v; }
  }
  __shared__ float r1[4], r2[4];
  #pragma unroll
  for (int o = 32; o > 0; o >>= 1) { cnt += __shfl_down(cnt, o, 64); sw += __shfl_down(sw, o, 64); }
  if ((tid & 63) == 0) { r1[tid >> 6] = cnt; r2[tid >> 6] = sw; }
  __syncthreads();
  if (tid == 0) {
    float c = r1[0] + r1[1] + r1[2] + r1[3];
    float s = r2[0] + r2[1] + r2[2] + r2[3];
    dis_bin[row] = rsqrtf(c + 1.0f);
    float d = rsqrtf(s + 1.0f);
    dc[row] = d;
    dr[row] = (s > 0.0f) ? d : 0.0f;
  }
}

// ---------------------------------------------------------------------------
// split f32 -> 3 bf16 planes
// ---------------------------------------------------------------------------
__global__ __launch_bounds__(256) void k_split3(
    const float* __restrict__ X, u16* __restrict__ Yh, u16* __restrict__ Ym,
    u16* __restrict__ Yl, long n4) {
  long i = (long)blockIdx.x * 256 + threadIdx.x;
  long stride = (long)gridDim.x * 256;
  for (; i < n4; i += stride) {
    f32x4 v = *(const f32x4*)(X + i * 4);
    u16x4 oh, om, ol;
    #pragma unroll
    for (int e = 0; e < 4; ++e) {
      float f = v[e];
      u16 h = f2b(f); float r1 = f - b2f(h);
      u16 m = f2b(r1); float r2 = r1 - b2f(m);
      u16 l = f2b(r2);
      oh[e] = h; om[e] = m; ol[e] = l;
    }
    *(u16x4*)(Yh + i * 4) = oh;
    *(u16x4*)(Ym + i * 4) = om;
    *(u16x4*)(Yl + i * 4) = ol;
  }
}

// transpose W1 [F][H] -> [H][F] with 3-way split
__global__ __launch_bounds__(256) void k_convT3(
    const float* __restrict__ X, u16* __restrict__ Yh, u16* __restrict__ Ym,
    u16* __restrict__ Yl) {
  __shared__ float tile[32][33];
  int tx = threadIdx.x & 31, ty = threadIdx.x >> 5;
  int r0 = blockIdx.y * 32, c0 = blockIdx.x * 32;
  #pragma unroll
  for (int i = 0; i < 4; ++i)
    tile[ty + i * 8][tx] = X[(long)(r0 + ty + i * 8) * H_ + (c0 + tx)];
  __syncthreads();
  #pragma unroll
  for (int i = 0; i < 4; ++i) {
    float v = tile[tx][ty + i * 8];
    long o = (long)(c0 + ty + i * 8) * F_ + (r0 + tx);
    u16 h = f2b(v); float r1 = v - b2f(h);
    u16 m = f2b(r1); float r2 = r1 - b2f(m);
    u16 l = f2b(r2);
    Yh[o] = h; Ym[o] = m; Yl[o] = l;
  }
}

// ---------------------------------------------------------------------------
// G1: P1raw = (A0+A1+A2) @ (B0+B1+B2)^T  (6-product split-3 MFMA)
// ---------------------------------------------------------------------------
__global__ __launch_bounds__(256) void mgemm64s3(
    const u16* __restrict__ A0, const u16* __restrict__ A1, const u16* __restrict__ A2,
    const u16* __restrict__ B0, const u16* __restrict__ B1, const u16* __restrict__ B2,
    float* __restrict__ C, int N, int K) {
  int m0 = blockIdx.y * 64, n0 = blockIdx.x * 64;
  __shared__ __align__(16) u16 As[3][64 * 72];
  __shared__ __align__(16) u16 Bs[3][64 * 72];
  const u16* Ap[3] = {A0 + (long)m0 * K, A1 + (long)m0 * K, A2 + (long)m0 * K};
  const u16* Bp[3] = {B0 + (long)n0 * K, B1 + (long)n0 * K, B2 + (long)n0 * K};
  int tid = threadIdx.x, lane = tid & 63, wave = tid >> 6;
  int wr = wave >> 1, wc = wave & 1, kg = lane >> 4, r16 = lane & 15;
  f32x4 acc[2][2] = {};

  for (int k0 = 0; k0 < K; k0 += 64) {
    #pragma unroll
    for (int t = 0; t < 3; ++t) {
      #pragma unroll
      for (int i = 0; i < 2; ++i) {
        int u = tid + i * 256;
        int row = u >> 3, seg = u & 7;
        *(u16x8*)(&As[t][row * 72 + seg * 8]) = *(const u16x8*)(Ap[t] + (long)row * K + k0 + seg * 8);
        *(u16x8*)(&Bs[t][row * 72 + seg * 8]) = *(const u16x8*)(Bp[t] + (long)row * K + k0 + seg * 8);
      }
    }
    __syncthreads();
    #pragma unroll
    for (int kk = 0; kk < 2; ++kk) {
      s16x8 ah[2], am[2], al[2], bh[2], bm2[2], bl[2];
      #pragma unroll
      for (int m = 0; m < 2; ++m) {
        int off = (wr * 32 + m * 16 + r16) * 72 + kk * 32 + kg * 8;
        ah[m] = *(const s16x8*)(&As[0][off]);
        am[m] = *(const s16x8*)(&As[1][off]);
        al[m] = *(const s16x8*)(&As[2][off]);
      }
      #pragma unroll
      for (int n = 0; n < 2; ++n) {
        int off = (wc * 32 + n * 16 + r16) * 72 + kk * 32 + kg * 8;
        bh[n] = *(const s16x8*)(&Bs[0][off]);
        bm2[n] = *(const s16x8*)(&Bs[1][off]);
        bl[n] = *(const s16x8*)(&Bs[2][off]);
      }
      #pragma unroll
      for (int m = 0; m < 2; ++m)
        #pragma unroll
        for (int n = 0; n < 2; ++n) {
          acc[m][n] = __builtin_amdgcn_mfma_f32_16x16x32_bf16(ah[m], bh[n], acc[m][n], 0, 0, 0);
          acc[m][n] = __builtin_amdgcn_mfma_f32_16x16x32_bf16(ah[m], bm2[n], acc[m][n], 0, 0, 0);
          acc[m][n] = __builtin_amdgcn_mfma_f32_16x16x32_bf16(am[m], bh[n], acc[m][n], 0, 0, 0);
          acc[m][n] = __builtin_amdgcn_mfma_f32_16x16x32_bf16(am[m], bm2[n], acc[m][n], 0, 0, 0);
          acc[m][n] = __builtin_amdgcn_mfma_f32_16x16x32_bf16(ah[m], bl[n], acc[m][n], 0, 0, 0);
          acc[m][n] = __builtin_amdgcn_mfma_f32_16x16x32_bf16(al[m], bh[n], acc[m][n], 0, 0, 0);
        }
    }
    __syncthreads();
  }

  #pragma unroll
  for (int m = 0; m < 2; ++m)
    #pragma unroll
    for (int r = 0; r < 4; ++r) {
      int row = m0 + wr * 32 + m * 16 + kg * 4 + r;
      #pragma unroll
      for (int n = 0; n < 2; ++n) {
        int col = n0 + wc * 32 + n * 16 + r16;
        C[(long)row * N + col] = acc[m][n][r];
      }
    }
}

// ---------------------------------------------------------------------------
// K2: x1 = relu(dis_i*(sum_{bit j} dis_j*P1_j + dis_i*P1_i) + b1)
// bitmask-driven; fused t[row] = x1_row . Watt
// ---------------------------------------------------------------------------
__global__ __launch_bounds__(256) void k_spmm_relu(
    const u64* __restrict__ bm, const float* __restrict__ P1,
    const float* __restrict__ dis_bin, const float* __restrict__ b1,
    const float* __restrict__ Watt, float* __restrict__ x1,
    float* __restrict__ t) {
  long row = blockIdx.x;
  int b = (int)(row >> 10), i = (int)(row & 1023);
  const float* Pb = P1 + (long)b * (long)N_ * H_;
  const float* db = dis_bin + (long)b * N_;
  __shared__ int idxs[N_];
  __shared__ int tcnt[256];
  __shared__ float accs[H_];
  int tid = threadIdx.x;
  int base = tid * 4;
  u64 word = bm[row * 16 + (tid >> 4)];
  int sh = base & 63;
  int f0 = (int)((word >> sh) & 1), f1 = (int)((word >> (sh + 1)) & 1);
  int f2 = (int)((word >> (sh + 2)) & 1), f3 = (int)((word >> (sh + 3)) & 1);
  int c0 = f0 + f1 + f2 + f3;
  tcnt[tid] = c0;
  __syncthreads();
  for (int off = 1; off < 256; off <<= 1) {
    int add = (tid >= off) ? tcnt[tid - off] : 0;
    __syncthreads();
    tcnt[tid] += add;
    __syncthreads();
  }
  int pos = tcnt[tid] - c0;
  int n = tcnt[255];
  if (f0) idxs[pos++] = base;
  if (f1) idxs[pos++] = base + 1;
  if (f2) idxs[pos++] = base + 2;
  if (f3) idxs[pos++] = base + 3;
  __syncthreads();
  int c = tid & 127, team = tid >> 7;
  float acc = 0.f;
  for (int u = team; u < n; u += 2) {
    int j = idxs[u];
    acc += db[j] * Pb[(long)j * H_ + c];
  }
  if (team == 1) accs[c] = acc;
  __syncthreads();
  float v = 0.f;
  if (team == 0) {
    float di = db[i];
    float tot = acc + accs[c] + di * Pb[(long)i * H_ + c];
    v = fmaxf(di * tot + b1[c], 0.0f);
    x1[row * H_ + c] = v;
  }
  __syncthreads();
  float prod = (team == 0) ? v * Watt[c] : 0.f;
  float s = blockReduceSum256(prod);
  if (tid == 0) t[row] = s;
}

// ---------------------------------------------------------------------------
// K5: alpha (bitmask-driven)
// ---------------------------------------------------------------------------
__global__ __launch_bounds__(256) void k_alpha(
    const u64* __restrict__ bm, const float* __restrict__ dis_bin,
    const float* __restrict__ t, const float* __restrict__ batt,
    float* __restrict__ alpha) {
  long row = blockIdx.x;
  int b = (int)(row >> 10), i = (int)(row & 1023);
  const float* db = dis_bin + (long)b * N_;
  const float* tb = t + (long)b * N_;
  int tid = threadIdx.x;
  float s = 0.f;
  #pragma unroll
  for (int it = 0; it < 4; ++it) {
    int j = tid + it * 256;
    u64 word = bm[row * 16 + (j >> 6)];
    if ((word >> (j & 63)) & 1) s += db[j] * tb[j];
  }
  s = blockReduceSum256(s);
  if (tid == 0) {
    float di = db[i];
    float pre = di * (s + di * tb[i]) + batt[0];
    float z = pre * pre;
    alpha[row] = 1.0f / (1.0f + expf(-z));
  }
}

// ---------------------------------------------------------------------------
// K6: top-k cut + mask (exact stable-sort semantics via composite key)
// ---------------------------------------------------------------------------
__global__ __launch_bounds__(1024) void k_cutmask2(
    const float* __restrict__ alpha, const int* __restrict__ num_sent,
    const int* __restrict__ nout, float* __restrict__ index_mask,
    float* __restrict__ ca) {
  int b = blockIdx.x, tid = threadIdx.x;
  __shared__ u64 keys[N_];
  __shared__ u64 red[N_];
  int ns = num_sent[b];
  float av = alpha[(long)b * N_ + tid];
  unsigned bits = __float_as_uint(av);
  u64 keyFull = ((u64)bits << 32) | (u64)(0xFFFFFFFFu - (unsigned)tid);
  keys[tid] = (tid < ns) ? keyFull : 0ULL;
  __syncthreads();
  int k = nout[0];
  u64 cutkey = 0;
  for (int r = 0; r < k; ++r) {
    red[tid] = keys[tid];
    __syncthreads();
    for (int off = 512; off > 0; off >>= 1) {
      if (tid < off) { u64 o = red[tid + off]; if (o > red[tid]) red[tid] = o; }
      __syncthreads();
    }
    u64 mx = red[0];
    __syncthreads();
    if (r == k - 1) cutkey = mx;
    else if (keys[tid] == mx) keys[tid] = 0ULL;
    __syncthreads();
  }
  float cutalpha = __uint_as_float((unsigned)(cutkey >> 32));
  index_mask[(long)b * N_ + tid] = (keyFull >= cutkey) ? 1.0f : 0.0f;
  ca[(long)b * N_ + tid] = fmaxf(av + 1e-7f - cutalpha, 0.0f);
}

// ---------------------------------------------------------------------------
// K7: S build + L1 row-normalize (coalesced f32 out only)
// ---------------------------------------------------------------------------
__global__ __launch_bounds__(256) void k_build_S(
    const float* __restrict__ adj, const float* __restrict__ dr,
    const float* __restrict__ dc, const float* __restrict__ ca,
    float* __restrict__ S) {
  long row = blockIdx.x;
  int b = (int)(row >> 10), i = (int)(row & 1023);
  const float* a = adj + row * N_;
  const float* dcb = dc + (long)b * N_;
  const float* cab = ca + (long)b * N_;
  float dri = dr[row];
  __shared__ float pre[N_];
  float ls = 0.f;
  for (int j = threadIdx.x; j < N_; j += 256) {
    float avv = a[j] + ((j == i) ? 1.0f : 0.0f);
    float v = dri * avv * dcb[j] * cab[j];
    pre[j] = v;
    ls += v;
  }
  float sum = blockReduceSum256(ls);
  float denom = fmaxf(sum, 1e-12f);
  for (int j = threadIdx.x; j < N_; j += 256)
    S[row * N_ + j] = pre[j] / denom;
}

// ---------------------------------------------------------------------------
// Big MFMA GEMM: 128x128 tile, BK=32, global_load_lds staging, XCD swizzle.
// B-operand rows (length K) at stride ldb (batch offset sB).
// MODE 1: bf16 C | 2: floorq + rowcnt + cbin(diag+1) | 3: tanh(sc*acc+bias) |
// 5: bf16 C = f2b(scale[col]*acc)
// ---------------------------------------------------------------------------
template<int MODE>
__global__ __launch_bounds__(256) void mgemm(
    const u16* __restrict__ A, const u16* __restrict__ Bt, void* __restrict__ Cv,
    int M, int N, int K, long sA, long sB, long sC, long ldb,
    const float* __restrict__ scale, const float* __restrict__ bias,
    int* __restrict__ rowcnt, u16* __restrict__ cbin) {
  // XCD-aware bijective chunked remap (total blocks divisible by 8)
  int gx = gridDim.x, gy = gridDim.y;
  int lin = (blockIdx.z * gy + blockIdx.y) * gx + blockIdx.x;
  int total = gx * gy * gridDim.z;
  int chunk = total >> 3;
  int swz = (lin & 7) * chunk + (lin >> 3);
  int bx = swz % gx; int t2 = swz / gx; int by = t2 % gy; int bz = t2 / gy;

  int m0 = by * 128, n0 = bx * 128;
  const u16* Ab = A + (long)bz * sA + (long)m0 * K;
  const u16* Bb = Bt + (long)bz * sB + (long)n0 * ldb;
  __shared__ __align__(16) u16 As[128 * 32];
  __shared__ __align__(16) u16 Bs[128 * 32];
  int tid = threadIdx.x;
  int lane = tid & 63, wave = tid >> 6;
  int wr = wave >> 1, wc = wave & 1;
  int kg = lane >> 4, r16 = lane & 15;
  const u16* ga = Ab + (long)(tid >> 2) * K + (tid & 3) * 8;
  const u16* gb = Bb + (long)(tid >> 2) * ldb + (tid & 3) * 8;
  f32x4 acc[4][4] = {};

  for (int k0 = 0; k0 < K; k0 += 32) {
    gload16(ga + k0, &As[tid * 8]);
    gload16(ga + (long)64 * K + k0, &As[2048 + tid * 8]);
    gload16(gb + k0, &Bs[tid * 8]);
    gload16(gb + (long)64 * ldb + k0, &Bs[2048 + tid * 8]);
    __syncthreads();
    s16x8 af[4], bfr[4];
    #pragma unroll
    for (int m = 0; m < 4; ++m)
      af[m] = *(const s16x8*)(&As[(wr * 64 + m * 16 + r16) * 32 + kg * 8]);
    #pragma unroll
    for (int n = 0; n < 4; ++n)
      bfr[n] = *(const s16x8*)(&Bs[(wc * 64 + n * 16 + r16) * 32 + kg * 8]);
    #pragma unroll
    for (int m = 0; m < 4; ++m)
      #pragma unroll
      for (int n = 0; n < 4; ++n)
        acc[m][n] = __builtin_amdgcn_mfma_f32_16x16x32_bf16(af[m], bfr[n], acc[m][n], 0, 0, 0);
    __syncthreads();
  }

  if constexpr (MODE == 2) {
    int* cnt = (int*)As;
    if (tid < 128) cnt[tid] = 0;
    __syncthreads();
    #pragma unroll
    for (int m = 0; m < 4; ++m) {
      #pragma unroll
      for (int r = 0; r < 4; ++r) {
        int lrow = wr * 64 + m * 16 + kg * 4 + r;
        int row = m0 + lrow;
        int nz = 0;
        #pragma unroll
        for (int n = 0; n < 4; ++n) {
          int col = n0 + wc * 64 + n * 16 + r16;
          float q = floorf(acc[m][n][r] * 10000.0f) / 10000.0f;
          long cidx = (long)bz * sC + (long)row * N + col;
          ((float*)Cv)[cidx] = q;
          bool qnz = (q != 0.0f);
          u16 bv;
          if (row == col) bv = qnz ? (u16)0x4000 : (u16)0x3F80;  // bin+I diag
          else            bv = qnz ? (u16)0x3F80 : (u16)0;
          cbin[cidx] = bv;
          nz += qnz ? 1 : 0;
        }
        atomicAdd(&cnt[lrow], nz);
      }
    }
    __syncthreads();
    if (tid < 128) atomicAdd(&rowcnt[(long)bz * N_ + m0 + tid], cnt[tid]);
    return;
  }

  #pragma unroll
  for (int m = 0; m < 4; ++m) {
    #pragma unroll
    for (int r = 0; r < 4; ++r) {
      int row = m0 + wr * 64 + m * 16 + kg * 4 + r;
      float sc = 0.f;
      if constexpr (MODE == 3) sc = scale[(long)bz * N_ + row];
      #pragma unroll
      for (int n = 0; n < 4; ++n) {
        int col = n0 + wc * 64 + n * 16 + r16;
        float v = acc[m][n][r];
        long cidx = (long)bz * sC + (long)row * N + col;
        if constexpr (MODE == 1) {
          ((u16*)Cv)[cidx] = f2b(v);
        } else if constexpr (MODE == 3) {
          ((float*)Cv)[cidx] = tanhf(sc * v + bias[col]);
        } else if constexpr (MODE == 5) {
          ((u16*)Cv)[cidx] = f2b(scale[col] * v);
        } else {
          ((float*)Cv)[cidx] = v;
        }
      }
    }
  }
}

// ---------------------------------------------------------------------------
// Small-N MFMA GEMM: 64x64 tile, BK=64, reg-staged, pad-72 LDS.
// f32 C + optional bf16 mirror.
// ---------------------------------------------------------------------------
__global__ __launch_bounds__(256) void mgemm64(
    const u16* __restrict__ A, const u16* __restrict__ Bt, float* __restrict__ C,
    int N, int K, long sA, long sB, long sC, u16* __restrict__ Cbf) {
  int bz = blockIdx.z;
  int m0 = blockIdx.y * 64, n0 = blockIdx.x * 64;
  const u16* Ab = A + (long)bz * sA + (long)m0 * K;
  const u16* Bb = Bt + (long)bz * sB + (long)n0 * K;
  __shared__ __align__(16) u16 As[64 * 72];
  __shared__ __align__(16) u16 Bs[64 * 72];
  int tid = threadIdx.x;
  int lane = tid & 63, wave = tid >> 6;
  int wr = wave >> 1, wc = wave & 1;
  int kg = lane >> 4, r16 = lane & 15;
  f32x4 acc[2][2] = {};

  for (int k0 = 0; k0 < K; k0 += 64) {
    #pragma unroll
    for (int i = 0; i < 2; ++i) {
      int u = tid + i * 256;
      int row = u >> 3, seg = u & 7;
      *(u16x8*)(&As[row * 72 + seg * 8]) = *(const u16x8*)(Ab + (long)row * K + k0 + seg * 8);
      *(u16x8*)(&Bs[row * 72 + seg * 8]) = *(const u16x8*)(Bb + (long)row * K + k0 + seg * 8);
    }
    __syncthreads();
    #pragma unroll
    for (int kk = 0; kk < 2; ++kk) {
      s16x8 af[2], bfr[2];
      #pragma unroll
      for (int m = 0; m < 2; ++m)
        af[m] = *(const s16x8*)(&As[(wr * 32 + m * 16 + r16) * 72 + kk * 32 + kg * 8]);
      #pragma unroll
      for (int n = 0; n < 2; ++n)
        bfr[n] = *(const s16x8*)(&Bs[(wc * 32 + n * 16 + r16) * 72 + kk * 32 + kg * 8]);
      #pragma unroll
      for (int m = 0; m < 2; ++m)
        #pragma unroll
        for (int n = 0; n < 2; ++n)
          acc[m][n] = __builtin_amdgcn_mfma_f32_16x16x32_bf16(af[m], bfr[n], acc[m][n], 0, 0, 0);
    }
    __syncthreads();
  }

  #pragma unroll
  for (int m = 0; m < 2; ++m)
    #pragma unroll
    for (int r = 0; r < 4; ++r) {
      int row = m0 + wr * 32 + m * 16 + kg * 4 + r;
      #pragma unroll
      for (int n = 0; n < 2; ++n) {
        int col = n0 + wc * 32 + n * 16 + r16;
        long cidx = (long)bz * sC + (long)row * N + col;
        float v = acc[m][n][r];
        C[cidx] = v;
        if (Cbf) Cbf[cidx] = f2b(v);
      }
    }
}

// ---------------------------------------------------------------------------
// transpose-convert: X[b][R][C] f32 -> Y[b][C][R] bf16 (LDS-staged, coalesced)
// ---------------------------------------------------------------------------
__global__ __launch_bounds__(256) void k_convT(
    const float* __restrict__ X, u16* __restrict__ Y, int R, int C,
    long sX, long sY) {
  __shared__ float tile[32][33];
  const float* Xb = X + (long)blockIdx.z * sX;
  u16* Yb = Y + (long)blockIdx.z * sY;
  int tx = threadIdx.x & 31, ty = threadIdx.x >> 5;
  int r0 = blockIdx.y * 32, c0 = blockIdx.x * 32;
  #pragma unroll
  for (int i = 0; i < 4; ++i)
    tile[ty + i * 8][tx] = Xb[(long)(r0 + ty + i * 8) * C + (c0 + tx)];
  __syncthreads();
  #pragma unroll
  for (int i = 0; i < 4; ++i)
    Yb[(long)(c0 + ty + i * 8) * R + (r0 + tx)] = f2b(tile[tx][ty + i * 8]);
}

// cnt -> dis2
__global__ __launch_bounds__(256) void k_cnt2dis(
    const int* __restrict__ cnt, float* __restrict__ dis2, int n) {
  int i = blockIdx.x * 256 + threadIdx.x;
  if (i < n) dis2[i] = rsqrtf(1.0f + (float)cnt[i]);
}

// ---------------------------------------------------------------------------
template<int W>
__global__ __launch_bounds__(256) void k_rowmean(
    const float* __restrict__ X, float* __restrict__ out) {
  long row = blockIdx.x;
  float s = 0.f;
  for (int j = threadIdx.x; j < W; j += 256) s += X[row * W + j];
  float r = blockReduceSum256(s);
  if (threadIdx.x == 0) out[row] = r / (float)W;
}

// ---------------------------------------------------------------------------
extern "C" void kernel_launch(void* const* d_in, const int* in_sizes, int n_in,
                              void* d_out, int out_size, void* d_ws, size_t ws_size,
                              hipStream_t stream) {
  const float* x     = (const float*)d_in[0];
  const float* adj   = (const float*)d_in[1];
  const int*   nsent = (const int*)d_in[2];
  const float* W1    = (const float*)d_in[3];
  const float* b1    = (const float*)d_in[4];
  const float* Watt  = (const float*)d_in[5];
  const float* batt  = (const float*)d_in[6];
  const float* W2    = (const float*)d_in[7];
  const float* b2    = (const float*)d_in[8];
  const int*   nout  = (const int*)d_in[9];

  const long NN = (long)N_ * N_;
  const long NH = (long)N_ * H_;
  const long NF = (long)N_ * F_;
  const int BN = B_ * N_;

  // output layout (flat concat, f32)
  float* out_x2   = (float*)d_out;
  float* out_cx   = out_x2 + (long)B_ * NF;
  float* out_cadj = out_cx + (long)B_ * NH;
  float* out_S    = out_cadj + (long)B_ * NN;
  float* out_im   = out_S + (long)B_ * NN;
  float* out_xs0  = out_im + BN;
  float* out_xs1  = out_xs0 + BN;

  // workspace (~142MB, proven scale)
  char* wsb = (char*)d_ws;
  float* P1      = (float*)wsb;
  float* x1      = P1 + (long)B_ * NH;
  float* t       = x1 + (long)B_ * NH;
  float* alpha   = t + BN;
  float* dis_bin = alpha + BN;
  float* dr      = dis_bin + BN;
  float* dc      = dr + BN;
  float* ca      = dc + BN;
  float* dis2    = ca + BN;
  int*   rowcnt  = (int*)(dis2 + BN);
  u64*   bm      = (u64*)(rowcnt + BN);       // 2MB bitmask
  char*  p       = (char*)(bm + (long)BN * 16);
  p = (char*)(((size_t)p + 255) & ~(size_t)255);
  u16* W1h   = (u16*)p;  p += (long)H_ * F_ * 2;
  u16* W1m   = (u16*)p;  p += (long)H_ * F_ * 2;
  u16* W1l   = (u16*)p;  p += (long)H_ * F_ * 2;
  u16* W2T   = (u16*)p;  p += (long)H_ * F_ * 2;
  u16* PT    = (u16*)p;  p += (long)B_ * NH * 2;   // x1T
  u16* St    = (u16*)p;  p += (long)B_ * NN * 2;   // xh -> St -> P2T
  u16* adjT  = (u16*)p;  p += (long)B_ * NN * 2;   // xm -> adjT -> cbin
  u16* xl3   = (u16*)p;                             // xl plane (24MB)
  u16* xh    = St;
  u16* xm    = adjT;
  u16* xl    = xl3;
  u16* cx_bf = (u16*)P1;       // P1 dead after spmm
  u16* x1T   = PT;
  u16* cbin  = adjT;           // adjT dead after G6
  u16* P2T   = St;             // St dead after G7; [F][BN] bf16 = 24MB
  u16* StA   = (u16*)out_x2;   // scratch in unwritten output region

  // split x and W1 into 3 bf16 planes
  k_split3<<<dim3(2048), dim3(256), 0, stream>>>(x, xh, xm, xl, (long)B_ * NF / 4);
  k_convT3<<<dim3(H_ / 32, F_ / 32, 1), dim3(256), 0, stream>>>(W1, W1h, W1m, W1l);

  hipMemsetAsync(rowcnt, 0, (size_t)BN * 4, stream);

  // G1: P1raw = x @ W1  (split-3 MFMA; dis applied in K2)
  mgemm64s3<<<dim3(H_ / 64, BN / 64, 1), dim3(256), 0, stream>>>(
      xh, xm, xl, W1h, W1m, W1l, P1, H_, F_);

  // K1: degrees + bitmask
  k_degrees<<<dim3(BN), dim3(256), 0, stream>>>(adj, dis_bin, dr, dc, bm);

  // K2: x1 + fused t (bitmask)
  k_spmm_relu<<<dim3(BN), dim3(256), 0, stream>>>(bm, P1, dis_bin, b1, Watt, x1, t);

  // alpha + top-k cut/mask + S
  k_alpha<<<dim3(BN), dim3(256), 0, stream>>>(bm, dis_bin, t, batt, alpha);
  k_cutmask2<<<dim3(B_), dim3(1024), 0, stream>>>(alpha, nsent, nout, out_im, ca);
  k_build_S<<<dim3(BN), dim3(256), 0, stream>>>(adj, dr, dc, ca, out_S);

  // transposes (LDS-staged, coalesced): St, x1T, adjT
  k_convT<<<dim3(N_ / 32, N_ / 32, B_), dim3(256), 0, stream>>>(out_S, St, N_, N_, NN, NN);
  k_convT<<<dim3(H_ / 32, N_ / 32, B_), dim3(256), 0, stream>>>(x1, x1T, N_, H_, NH, NH);
  k_convT<<<dim3(N_ / 32, N_ / 32, B_), dim3(256), 0, stream>>>(adj, adjT, N_, N_, NN, NN);

  // G5: coarse_x = S^T @ x1 + fused cx_bf
  mgemm64<<<dim3(H_ / 64, N_ / 64, B_), dim3(256), 0, stream>>>(
      St, x1T, out_cx, H_, N_, NN, NH, NH, cx_bf);
  k_rowmean<H_><<<dim3(BN), dim3(256), 0, stream>>>(out_cx, out_xs0);

  // G6: StA = S^T @ adj (bf16 out)
  mgemm<1><<<dim3(N_ / 128, N_ / 128, B_), dim3(256), 0, stream>>>(
      St, adjT, StA, N_, N_, N_, NN, NN, NN, N_, nullptr, nullptr, nullptr, nullptr);

  // G7: coarse_adj = floorq(StA @ S) + rowcnt + cbin(diag+1) (-> adjT region)
  mgemm<2><<<dim3(N_ / 128, N_ / 128, B_), dim3(256), 0, stream>>>(
      StA, St, out_cadj, N_, N_, N_, NN, NN, NN, N_, nullptr, nullptr, rowcnt, cbin);

  k_cnt2dis<<<dim3((BN + 255) / 256), dim3(256), 0, stream>>>(rowcnt, dis2, BN);

  // W2T  [F][H] bf16
  k_convT<<<dim3(F_ / 32, H_ / 32, 1), dim3(256), 0, stream>>>(W2, W2T, H_, F_, 0, 0);

  // G8' (transposed role): P2T[f][r] = f2b(dis2[r] * (W2T[f] . cx_bf[r]))
  //   M=F, N=BN, K=H, z=1; output bf16 [F][BN] directly in G9's B layout.
  mgemm<5><<<dim3(BN / 128, F_ / 128, 1), dim3(256), 0, stream>>>(
      W2T, cx_bf, P2T, F_, BN, H_, 0, 0, 0, H_, dis2, nullptr, nullptr, nullptr);

  // G9: x2 = tanh(dis2_i * (cbin' @ P2) + b2)  (diag folded; B rows at ldb=BN)
  mgemm<3><<<dim3(F_ / 128, N_ / 128, B_), dim3(256), 0, stream>>>(
      cbin, P2T, out_x2, N_, F_, N_, NN, N_, NF, (long)BN, dis2, b2,
      nullptr, nullptr);

  k_rowmean<F_><<<dim3(BN), dim3(256), 0, stream>>>(out_x2, out_xs1);
}

// Round 10
// 440.900 us; speedup vs baseline: 1.6234x; 1.0534x over previous
//
#include <hip/hip_runtime.h>

#define B_ 16
#define N_ 1024
#define F_ 768
#define H_ 128

typedef float f32x4 __attribute__((ext_vector_type(4)));
typedef short s16x8 __attribute__((ext_vector_type(8)));
typedef unsigned short u16;
typedef u16 u16x8 __attribute__((ext_vector_type(8)));
typedef u16 u16x4 __attribute__((ext_vector_type(4)));
typedef unsigned long long u64;

__device__ __forceinline__ u16 f2b(float f) {
  unsigned u = __float_as_uint(f);
  unsigned r = (u + 0x7FFFu + ((u >> 16) & 1u)) >> 16;
  return (u16)r;
}
__device__ __forceinline__ float b2f(u16 u) {
  return __uint_as_float(((unsigned)u) << 16);
}

__device__ __forceinline__ void gload16(const u16* g, u16* l) {
  __builtin_amdgcn_global_load_lds(
      (const __attribute__((address_space(1))) unsigned int*)g,
      (__attribute__((address_space(3))) unsigned int*)l, 16, 0, 0);
}

// ---------------------------------------------------------------------------
__device__ __forceinline__ float blockReduceSum256(float v) {
  __shared__ float red[4];
  #pragma unroll
  for (int o = 32; o > 0; o >>= 1) v += __shfl_down(v, o, 64);
  if ((threadIdx.x & 63) == 0) red[threadIdx.x >> 6] = v;
  __syncthreads();
  float r = red[0] + red[1] + red[2] + red[3];
  __syncthreads();
  return r;
}

// ---------------------------------------------------------------------------
// K1: degrees + bitmask + coalesced adj_bf (bf16, row-major) emission
// ---------------------------------------------------------------------------
__global__ __launch_bounds__(256) void k_degrees(
    const float* __restrict__ adj, float* __restrict__ dis_bin,
    float* __restrict__ dr, float* __restrict__ dc, u64* __restrict__ bm,
    u16* __restrict__ adj_bf) {
  long row = blockIdx.x;
  const float* a = adj + row * N_;
  u16* ab = adj_bf + row * N_;
  int tid = threadIdx.x;
  float cnt = 0.f, sw = 0.f;
  #pragma unroll
  for (int it = 0; it < 4; ++it) {
    int j = tid + it * 256;
    float v = a[j];
    ab[j] = f2b(v);
    bool nz = (v != 0.0f);
    u64 ball = __ballot(nz);
    if ((tid & 63) == 0) bm[row * 16 + it * 4 + (tid >> 6)] = ball;
    if (nz) { cnt += 1.0f; sw += v; }
  }
  __shared__ float r1[4], r2[4];
  #pragma unroll
  for (int o = 32; o > 0; o >>= 1) { cnt += __shfl_down(cnt, o, 64); sw += __shfl_down(sw, o, 64); }
  if ((tid & 63) == 0) { r1[tid >> 6] = cnt; r2[tid >> 6] = sw; }
  __syncthreads();
  if (tid == 0) {
    float c = r1[0] + r1[1] + r1[2] + r1[3];
    float s = r2[0] + r2[1] + r2[2] + r2[3];
    dis_bin[row] = rsqrtf(c + 1.0f);
    float d = rsqrtf(s + 1.0f);
    dc[row] = d;
    dr[row] = (s > 0.0f) ? d : 0.0f;
  }
}

// ---------------------------------------------------------------------------
// split f32 -> 3 bf16 planes
// ---------------------------------------------------------------------------
__global__ __launch_bounds__(256) void k_split3(
    const float* __restrict__ X, u16* __restrict__ Yh, u16* __restrict__ Ym,
    u16* __restrict__ Yl, long n4) {
  long i = (long)blockIdx.x * 256 + threadIdx.x;
  long stride = (long)gridDim.x * 256;
  for (; i < n4; i += stride) {
    f32x4 v = *(const f32x4*)(X + i * 4);
    u16x4 oh, om, ol;
    #pragma unroll
    for (int e = 0; e < 4; ++e) {
      float f = v[e];
      u16 h = f2b(f); float r1 = f - b2f(h);
      u16 m = f2b(r1); float r2 = r1 - b2f(m);
      u16 l = f2b(r2);
      oh[e] = h; om[e] = m; ol[e] = l;
    }
    *(u16x4*)(Yh + i * 4) = oh;
    *(u16x4*)(Ym + i * 4) = om;
    *(u16x4*)(Yl + i * 4) = ol;
  }
}

// transpose W1 [F][H] -> [H][F] with 3-way split
__global__ __launch_bounds__(256) void k_convT3(
    const float* __restrict__ X, u16* __restrict__ Yh, u16* __restrict__ Ym,
    u16* __restrict__ Yl) {
  __shared__ float tile[32][33];
  int tx = threadIdx.x & 31, ty = threadIdx.x >> 5;
  int r0 = blockIdx.y * 32, c0 = blockIdx.x * 32;
  #pragma unroll
  for (int i = 0; i < 4; ++i)
    tile[ty + i * 8][tx] = X[(long)(r0 + ty + i * 8) * H_ + (c0 + tx)];
  __syncthreads();
  #pragma unroll
  for (int i = 0; i < 4; ++i) {
    float v = tile[tx][ty + i * 8];
    long o = (long)(c0 + ty + i * 8) * F_ + (r0 + tx);
    u16 h = f2b(v); float r1 = v - b2f(h);
    u16 m = f2b(r1); float r2 = r1 - b2f(m);
    u16 l = f2b(r2);
    Yh[o] = h; Ym[o] = m; Yl[o] = l;
  }
}

// ---------------------------------------------------------------------------
// G1: P1raw = (A0+A1+A2) @ (B0+B1+B2)^T  (6-product split-3 MFMA)
// ---------------------------------------------------------------------------
__global__ __launch_bounds__(256) void mgemm64s3(
    const u16* __restrict__ A0, const u16* __restrict__ A1, const u16* __restrict__ A2,
    const u16* __restrict__ B0, const u16* __restrict__ B1, const u16* __restrict__ B2,
    float* __restrict__ C, int N, int K) {
  int m0 = blockIdx.y * 64, n0 = blockIdx.x * 64;
  __shared__ __align__(16) u16 As[3][64 * 72];
  __shared__ __align__(16) u16 Bs[3][64 * 72];
  const u16* Ap[3] = {A0 + (long)m0 * K, A1 + (long)m0 * K, A2 + (long)m0 * K};
  const u16* Bp[3] = {B0 + (long)n0 * K, B1 + (long)n0 * K, B2 + (long)n0 * K};
  int tid = threadIdx.x, lane = tid & 63, wave = tid >> 6;
  int wr = wave >> 1, wc = wave & 1, kg = lane >> 4, r16 = lane & 15;
  f32x4 acc[2][2] = {};

  for (int k0 = 0; k0 < K; k0 += 64) {
    #pragma unroll
    for (int t = 0; t < 3; ++t) {
      #pragma unroll
      for (int i = 0; i < 2; ++i) {
        int u = tid + i * 256;
        int row = u >> 3, seg = u & 7;
        *(u16x8*)(&As[t][row * 72 + seg * 8]) = *(const u16x8*)(Ap[t] + (long)row * K + k0 + seg * 8);
        *(u16x8*)(&Bs[t][row * 72 + seg * 8]) = *(const u16x8*)(Bp[t] + (long)row * K + k0 + seg * 8);
      }
    }
    __syncthreads();
    #pragma unroll
    for (int kk = 0; kk < 2; ++kk) {
      s16x8 ah[2], am[2], al[2], bh[2], bm2[2], bl[2];
      #pragma unroll
      for (int m = 0; m < 2; ++m) {
        int off = (wr * 32 + m * 16 + r16) * 72 + kk * 32 + kg * 8;
        ah[m] = *(const s16x8*)(&As[0][off]);
        am[m] = *(const s16x8*)(&As[1][off]);
        al[m] = *(const s16x8*)(&As[2][off]);
      }
      #pragma unroll
      for (int n = 0; n < 2; ++n) {
        int off = (wc * 32 + n * 16 + r16) * 72 + kk * 32 + kg * 8;
        bh[n] = *(const s16x8*)(&Bs[0][off]);
        bm2[n] = *(const s16x8*)(&Bs[1][off]);
        bl[n] = *(const s16x8*)(&Bs[2][off]);
      }
      #pragma unroll
      for (int m = 0; m < 2; ++m)
        #pragma unroll
        for (int n = 0; n < 2; ++n) {
          acc[m][n] = __builtin_amdgcn_mfma_f32_16x16x32_bf16(ah[m], bh[n], acc[m][n], 0, 0, 0);
          acc[m][n] = __builtin_amdgcn_mfma_f32_16x16x32_bf16(ah[m], bm2[n], acc[m][n], 0, 0, 0);
          acc[m][n] = __builtin_amdgcn_mfma_f32_16x16x32_bf16(am[m], bh[n], acc[m][n], 0, 0, 0);
          acc[m][n] = __builtin_amdgcn_mfma_f32_16x16x32_bf16(am[m], bm2[n], acc[m][n], 0, 0, 0);
          acc[m][n] = __builtin_amdgcn_mfma_f32_16x16x32_bf16(ah[m], bl[n], acc[m][n], 0, 0, 0);
          acc[m][n] = __builtin_amdgcn_mfma_f32_16x16x32_bf16(al[m], bh[n], acc[m][n], 0, 0, 0);
        }
    }
    __syncthreads();
  }

  #pragma unroll
  for (int m = 0; m < 2; ++m)
    #pragma unroll
    for (int r = 0; r < 4; ++r) {
      int row = m0 + wr * 32 + m * 16 + kg * 4 + r;
      #pragma unroll
      for (int n = 0; n < 2; ++n) {
        int col = n0 + wc * 32 + n * 16 + r16;
        C[(long)row * N + col] = acc[m][n][r];
      }
    }
}

// ---------------------------------------------------------------------------
// K2: x1 = relu(dis_i*(sum_{bit j} dis_j*P1_j + dis_i*P1_i) + b1)
// bitmask-driven; wave-level scan; fused t[row] = x1_row . Watt
// ---------------------------------------------------------------------------
__global__ __launch_bounds__(256) void k_spmm_relu(
    const u64* __restrict__ bm, const float* __restrict__ P1,
    const float* __restrict__ dis_bin, const float* __restrict__ b1,
    const float* __restrict__ Watt, float* __restrict__ x1,
    float* __restrict__ t) {
  long row = blockIdx.x;
  int b = (int)(row >> 10), i = (int)(row & 1023);
  const float* Pb = P1 + (long)b * (long)N_ * H_;
  const float* db = dis_bin + (long)b * N_;
  __shared__ int idxs[N_];
  __shared__ int wtot[4];
  __shared__ float accs[H_];
  int tid = threadIdx.x;
  int wid = tid >> 6, lane = tid & 63;
  int base = tid * 4;
  u64 word = bm[row * 16 + (tid >> 4)];
  int sh = base & 63;
  int f0 = (int)((word >> sh) & 1), f1 = (int)((word >> (sh + 1)) & 1);
  int f2 = (int)((word >> (sh + 2)) & 1), f3 = (int)((word >> (sh + 3)) & 1);
  int c0 = f0 + f1 + f2 + f3;
  // wave-level inclusive scan of c0
  int inc = c0;
  #pragma unroll
  for (int o = 1; o < 64; o <<= 1) {
    int v = __shfl_up(inc, o, 64);
    if (lane >= o) inc += v;
  }
  if (lane == 63) wtot[wid] = inc;
  __syncthreads();
  int wbase = 0;
  #pragma unroll
  for (int w = 0; w < 4; ++w) wbase += (w < wid) ? wtot[w] : 0;
  int pos = wbase + inc - c0;
  int n = wtot[0] + wtot[1] + wtot[2] + wtot[3];
  if (f0) idxs[pos++] = base;
  if (f1) idxs[pos++] = base + 1;
  if (f2) idxs[pos++] = base + 2;
  if (f3) idxs[pos++] = base + 3;
  __syncthreads();
  int c = tid & 127, team = tid >> 7;
  float acc = 0.f;
  for (int u = team; u < n; u += 2) {
    int j = idxs[u];
    acc += db[j] * Pb[(long)j * H_ + c];
  }
  if (team == 1) accs[c] = acc;
  __syncthreads();
  float v = 0.f;
  if (team == 0) {
    float di = db[i];
    float tot = acc + accs[c] + di * Pb[(long)i * H_ + c];
    v = fmaxf(di * tot + b1[c], 0.0f);
    x1[row * H_ + c] = v;
  }
  __syncthreads();
  float prod = (team == 0) ? v * Watt[c] : 0.f;
  float s = blockReduceSum256(prod);
  if (tid == 0) t[row] = s;
}

// ---------------------------------------------------------------------------
// K5: alpha (bitmask-driven)
// ---------------------------------------------------------------------------
__global__ __launch_bounds__(256) void k_alpha(
    const u64* __restrict__ bm, const float* __restrict__ dis_bin,
    const float* __restrict__ t, const float* __restrict__ batt,
    float* __restrict__ alpha) {
  long row = blockIdx.x;
  int b = (int)(row >> 10), i = (int)(row & 1023);
  const float* db = dis_bin + (long)b * N_;
  const float* tb = t + (long)b * N_;
  int tid = threadIdx.x;
  float s = 0.f;
  #pragma unroll
  for (int it = 0; it < 4; ++it) {
    int j = tid + it * 256;
    u64 word = bm[row * 16 + (j >> 6)];
    if ((word >> (j & 63)) & 1) s += db[j] * tb[j];
  }
  s = blockReduceSum256(s);
  if (tid == 0) {
    float di = db[i];
    float pre = di * (s + di * tb[i]) + batt[0];
    float z = pre * pre;
    alpha[row] = 1.0f / (1.0f + expf(-z));
  }
}

// ---------------------------------------------------------------------------
// K6: top-k cut + mask (exact stable-sort semantics via composite key)
// ---------------------------------------------------------------------------
__global__ __launch_bounds__(1024) void k_cutmask2(
    const float* __restrict__ alpha, const int* __restrict__ num_sent,
    const int* __restrict__ nout, float* __restrict__ index_mask,
    float* __restrict__ ca) {
  int b = blockIdx.x, tid = threadIdx.x;
  __shared__ u64 keys[N_];
  __shared__ u64 red[N_];
  int ns = num_sent[b];
  float av = alpha[(long)b * N_ + tid];
  unsigned bits = __float_as_uint(av);
  u64 keyFull = ((u64)bits << 32) | (u64)(0xFFFFFFFFu - (unsigned)tid);
  keys[tid] = (tid < ns) ? keyFull : 0ULL;
  __syncthreads();
  int k = nout[0];
  u64 cutkey = 0;
  for (int r = 0; r < k; ++r) {
    red[tid] = keys[tid];
    __syncthreads();
    for (int off = 512; off > 0; off >>= 1) {
      if (tid < off) { u64 o = red[tid + off]; if (o > red[tid]) red[tid] = o; }
      __syncthreads();
    }
    u64 mx = red[0];
    __syncthreads();
    if (r == k - 1) cutkey = mx;
    else if (keys[tid] == mx) keys[tid] = 0ULL;
    __syncthreads();
  }
  float cutalpha = __uint_as_float((unsigned)(cutkey >> 32));
  index_mask[(long)b * N_ + tid] = (keyFull >= cutkey) ? 1.0f : 0.0f;
  ca[(long)b * N_ + tid] = fmaxf(av + 1e-7f - cutalpha, 0.0f);
}

// ---------------------------------------------------------------------------
// K7: S build + L1 row-normalize (coalesced f32 out only)
// ---------------------------------------------------------------------------
__global__ __launch_bounds__(256) void k_build_S(
    const float* __restrict__ adj, const float* __restrict__ dr,
    const float* __restrict__ dc, const float* __restrict__ ca,
    float* __restrict__ S) {
  long row = blockIdx.x;
  int b = (int)(row >> 10), i = (int)(row & 1023);
  const float* a = adj + row * N_;
  const float* dcb = dc + (long)b * N_;
  const float* cab = ca + (long)b * N_;
  float dri = dr[row];
  __shared__ float pre[N_];
  float ls = 0.f;
  for (int j = threadIdx.x; j < N_; j += 256) {
    float avv = a[j] + ((j == i) ? 1.0f : 0.0f);
    float v = dri * avv * dcb[j] * cab[j];
    pre[j] = v;
    ls += v;
  }
  float sum = blockReduceSum256(ls);
  float denom = fmaxf(sum, 1e-12f);
  for (int j = threadIdx.x; j < N_; j += 256)
    S[row * N_ + j] = pre[j] / denom;
}

// ---------------------------------------------------------------------------
// Big MFMA GEMM: 128x128 tile, BK=32, global_load_lds staging, XCD swizzle.
// B-operand rows (length K) at stride ldb (batch offset sB).
// MODE 1: bf16 C | 2: floorq + rowcnt + cbin(diag+1) |
// 3: f32 tanh(rsqrt(1+cnt[row])*acc + bias[col]) |
// 5: bf16 f2b(rsqrt(1+cnt[col])*acc)
// ---------------------------------------------------------------------------
template<int MODE>
__global__ __launch_bounds__(256) void mgemm(
    const u16* __restrict__ A, const u16* __restrict__ Bt, void* __restrict__ Cv,
    int M, int N, int K, long sA, long sB, long sC, long ldb,
    const int* __restrict__ cnt, const float* __restrict__ bias,
    int* __restrict__ rowcnt, u16* __restrict__ cbin) {
  // XCD-aware bijective chunked remap (total blocks divisible by 8)
  int gx = gridDim.x, gy = gridDim.y;
  int lin = (blockIdx.z * gy + blockIdx.y) * gx + blockIdx.x;
  int total = gx * gy * gridDim.z;
  int chunk = total >> 3;
  int swz = (lin & 7) * chunk + (lin >> 3);
  int bx = swz % gx; int t2 = swz / gx; int by = t2 % gy; int bz = t2 / gy;

  int m0 = by * 128, n0 = bx * 128;
  const u16* Ab = A + (long)bz * sA + (long)m0 * K;
  const u16* Bb = Bt + (long)bz * sB + (long)n0 * ldb;
  __shared__ __align__(16) u16 As[128 * 32];
  __shared__ __align__(16) u16 Bs[128 * 32];
  int tid = threadIdx.x;
  int lane = tid & 63, wave = tid >> 6;
  int wr = wave >> 1, wc = wave & 1;
  int kg = lane >> 4, r16 = lane & 15;
  const u16* ga = Ab + (long)(tid >> 2) * K + (tid & 3) * 8;
  const u16* gb = Bb + (long)(tid >> 2) * ldb + (tid & 3) * 8;
  f32x4 acc[4][4] = {};

  for (int k0 = 0; k0 < K; k0 += 32) {
    gload16(ga + k0, &As[tid * 8]);
    gload16(ga + (long)64 * K + k0, &As[2048 + tid * 8]);
    gload16(gb + k0, &Bs[tid * 8]);
    gload16(gb + (long)64 * ldb + k0, &Bs[2048 + tid * 8]);
    __syncthreads();
    s16x8 af[4], bfr[4];
    #pragma unroll
    for (int m = 0; m < 4; ++m)
      af[m] = *(const s16x8*)(&As[(wr * 64 + m * 16 + r16) * 32 + kg * 8]);
    #pragma unroll
    for (int n = 0; n < 4; ++n)
      bfr[n] = *(const s16x8*)(&Bs[(wc * 64 + n * 16 + r16) * 32 + kg * 8]);
    #pragma unroll
    for (int m = 0; m < 4; ++m)
      #pragma unroll
      for (int n = 0; n < 4; ++n)
        acc[m][n] = __builtin_amdgcn_mfma_f32_16x16x32_bf16(af[m], bfr[n], acc[m][n], 0, 0, 0);
    __syncthreads();
  }

  if constexpr (MODE == 2) {
    int* cntl = (int*)As;
    if (tid < 128) cntl[tid] = 0;
    __syncthreads();
    #pragma unroll
    for (int m = 0; m < 4; ++m) {
      #pragma unroll
      for (int r = 0; r < 4; ++r) {
        int lrow = wr * 64 + m * 16 + kg * 4 + r;
        int row = m0 + lrow;
        int nz = 0;
        #pragma unroll
        for (int n = 0; n < 4; ++n) {
          int col = n0 + wc * 64 + n * 16 + r16;
          float q = floorf(acc[m][n][r] * 10000.0f) / 10000.0f;
          long cidx = (long)bz * sC + (long)row * N + col;
          ((float*)Cv)[cidx] = q;
          bool qnz = (q != 0.0f);
          u16 bv;
          if (row == col) bv = qnz ? (u16)0x4000 : (u16)0x3F80;  // bin+I diag
          else            bv = qnz ? (u16)0x3F80 : (u16)0;
          cbin[cidx] = bv;
          nz += qnz ? 1 : 0;
        }
        atomicAdd(&cntl[lrow], nz);
      }
    }
    __syncthreads();
    if (tid < 128) atomicAdd(&rowcnt[(long)bz * N_ + m0 + tid], cntl[tid]);
    return;
  }

  #pragma unroll
  for (int m = 0; m < 4; ++m) {
    #pragma unroll
    for (int r = 0; r < 4; ++r) {
      int row = m0 + wr * 64 + m * 16 + kg * 4 + r;
      float sc = 0.f;
      if constexpr (MODE == 3)
        sc = rsqrtf(1.0f + (float)cnt[(long)bz * N_ + row]);
      #pragma unroll
      for (int n = 0; n < 4; ++n) {
        int col = n0 + wc * 64 + n * 16 + r16;
        float v = acc[m][n][r];
        long cidx = (long)bz * sC + (long)row * N + col;
        if constexpr (MODE == 1) {
          ((u16*)Cv)[cidx] = f2b(v);
        } else if constexpr (MODE == 3) {
          ((float*)Cv)[cidx] = tanhf(sc * v + bias[col]);
        } else if constexpr (MODE == 5) {
          float scc = rsqrtf(1.0f + (float)cnt[col]);
          ((u16*)Cv)[cidx] = f2b(scc * v);
        } else {
          ((float*)Cv)[cidx] = v;
        }
      }
    }
  }
}

// ---------------------------------------------------------------------------
// Small-N MFMA GEMM: 64x64 tile, BK=64, reg-staged, pad-72 LDS.
// f32 C + optional bf16 mirror.
// ---------------------------------------------------------------------------
__global__ __launch_bounds__(256) void mgemm64(
    const u16* __restrict__ A, const u16* __restrict__ Bt, float* __restrict__ C,
    int N, int K, long sA, long sB, long sC, u16* __restrict__ Cbf) {
  int bz = blockIdx.z;
  int m0 = blockIdx.y * 64, n0 = blockIdx.x * 64;
  const u16* Ab = A + (long)bz * sA + (long)m0 * K;
  const u16* Bb = Bt + (long)bz * sB + (long)n0 * K;
  __shared__ __align__(16) u16 As[64 * 72];
  __shared__ __align__(16) u16 Bs[64 * 72];
  int tid = threadIdx.x;
  int lane = tid & 63, wave = tid >> 6;
  int wr = wave >> 1, wc = wave & 1;
  int kg = lane >> 4, r16 = lane & 15;
  f32x4 acc[2][2] = {};

  for (int k0 = 0; k0 < K; k0 += 64) {
    #pragma unroll
    for (int i = 0; i < 2; ++i) {
      int u = tid + i * 256;
      int row = u >> 3, seg = u & 7;
      *(u16x8*)(&As[row * 72 + seg * 8]) = *(const u16x8*)(Ab + (long)row * K + k0 + seg * 8);
      *(u16x8*)(&Bs[row * 72 + seg * 8]) = *(const u16x8*)(Bb + (long)row * K + k0 + seg * 8);
    }
    __syncthreads();
    #pragma unroll
    for (int kk = 0; kk < 2; ++kk) {
      s16x8 af[2], bfr[2];
      #pragma unroll
      for (int m = 0; m < 2; ++m)
        af[m] = *(const s16x8*)(&As[(wr * 32 + m * 16 + r16) * 72 + kk * 32 + kg * 8]);
      #pragma unroll
      for (int n = 0; n < 2; ++n)
        bfr[n] = *(const s16x8*)(&Bs[(wc * 32 + n * 16 + r16) * 72 + kk * 32 + kg * 8]);
      #pragma unroll
      for (int m = 0; m < 2; ++m)
        #pragma unroll
        for (int n = 0; n < 2; ++n)
          acc[m][n] = __builtin_amdgcn_mfma_f32_16x16x32_bf16(af[m], bfr[n], acc[m][n], 0, 0, 0);
    }
    __syncthreads();
  }

  #pragma unroll
  for (int m = 0; m < 2; ++m)
    #pragma unroll
    for (int r = 0; r < 4; ++r) {
      int row = m0 + wr * 32 + m * 16 + kg * 4 + r;
      #pragma unroll
      for (int n = 0; n < 2; ++n) {
        int col = n0 + wc * 32 + n * 16 + r16;
        long cidx = (long)bz * sC + (long)row * N + col;
        float v = acc[m][n][r];
        C[cidx] = v;
        if (Cbf) Cbf[cidx] = f2b(v);
      }
    }
}

// ---------------------------------------------------------------------------
// transpose-convert: X[b][R][C] f32 -> Y[b][C][R] bf16 (LDS-staged, coalesced)
// ---------------------------------------------------------------------------
__global__ __launch_bounds__(256) void k_convT(
    const float* __restrict__ X, u16* __restrict__ Y, int R, int C,
    long sX, long sY) {
  __shared__ float tile[32][33];
  const float* Xb = X + (long)blockIdx.z * sX;
  u16* Yb = Y + (long)blockIdx.z * sY;
  int tx = threadIdx.x & 31, ty = threadIdx.x >> 5;
  int r0 = blockIdx.y * 32, c0 = blockIdx.x * 32;
  #pragma unroll
  for (int i = 0; i < 4; ++i)
    tile[ty + i * 8][tx] = Xb[(long)(r0 + ty + i * 8) * C + (c0 + tx)];
  __syncthreads();
  #pragma unroll
  for (int i = 0; i < 4; ++i)
    Yb[(long)(c0 + ty + i * 8) * R + (r0 + tx)] = f2b(tile[tx][ty + i * 8]);
}

// ---------------------------------------------------------------------------
template<int W>
__global__ __launch_bounds__(256) void k_rowmean(
    const float* __restrict__ X, float* __restrict__ out) {
  long row = blockIdx.x;
  float s = 0.f;
  for (int j = threadIdx.x; j < W; j += 256) s += X[row * W + j];
  float r = blockReduceSum256(s);
  if (threadIdx.x == 0) out[row] = r / (float)W;
}

// ---------------------------------------------------------------------------
extern "C" void kernel_launch(void* const* d_in, const int* in_sizes, int n_in,
                              void* d_out, int out_size, void* d_ws, size_t ws_size,
                              hipStream_t stream) {
  const float* x     = (const float*)d_in[0];
  const float* adj   = (const float*)d_in[1];
  const int*   nsent = (const int*)d_in[2];
  const float* W1    = (const float*)d_in[3];
  const float* b1    = (const float*)d_in[4];
  const float* Watt  = (const float*)d_in[5];
  const float* batt  = (const float*)d_in[6];
  const float* W2    = (const float*)d_in[7];
  const float* b2    = (const float*)d_in[8];
  const int*   nout  = (const int*)d_in[9];

  const long NN = (long)N_ * N_;
  const long NH = (long)N_ * H_;
  const long NF = (long)N_ * F_;
  const int BN = B_ * N_;

  // output layout (flat concat, f32)
  float* out_x2   = (float*)d_out;
  float* out_cx   = out_x2 + (long)B_ * NF;
  float* out_cadj = out_cx + (long)B_ * NH;
  float* out_S    = out_cadj + (long)B_ * NN;
  float* out_im   = out_S + (long)B_ * NN;
  float* out_xs0  = out_im + BN;
  float* out_xs1  = out_xs0 + BN;

  // workspace (~142MB, proven scale)
  char* wsb = (char*)d_ws;
  float* P1      = (float*)wsb;
  float* x1      = P1 + (long)B_ * NH;
  float* t       = x1 + (long)B_ * NH;
  float* alpha   = t + BN;
  float* dis_bin = alpha + BN;
  float* dr      = dis_bin + BN;
  float* dc      = dr + BN;
  float* ca      = dc + BN;
  int*   rowcnt  = (int*)(ca + BN);
  u64*   bm      = (u64*)(rowcnt + BN);       // 2MB bitmask
  char*  p       = (char*)(bm + (long)BN * 16);
  p = (char*)(((size_t)p + 255) & ~(size_t)255);
  u16* W1h   = (u16*)p;  p += (long)H_ * F_ * 2;
  u16* W1m   = (u16*)p;  p += (long)H_ * F_ * 2;
  u16* W1l   = (u16*)p;  p += (long)H_ * F_ * 2;
  u16* W2T   = (u16*)p;  p += (long)H_ * F_ * 2;
  u16* PT    = (u16*)p;  p += (long)B_ * NH * 2;   // x1T
  u16* St    = (u16*)p;  p += (long)B_ * NN * 2;   // xh -> St -> P2T
  u16* adjBF = (u16*)p;  p += (long)B_ * NN * 2;   // xm -> adj_bf -> cbin
  u16* xl3   = (u16*)p;                             // xl plane (24MB)
  u16* xh    = St;
  u16* xm    = adjBF;
  u16* xl    = xl3;
  u16* cx_bf = (u16*)P1;       // P1 dead after spmm
  u16* x1T   = PT;
  u16* cbin  = adjBF;          // adj_bf dead after G6'
  u16* P2T   = St;             // St dead after G7'
  u16* M1t   = (u16*)out_x2;   // scratch in unwritten output region (32MB)

  // split x and W1 into 3 bf16 planes
  k_split3<<<dim3(2048), dim3(256), 0, stream>>>(x, xh, xm, xl, (long)B_ * NF / 4);
  k_convT3<<<dim3(H_ / 32, F_ / 32, 1), dim3(256), 0, stream>>>(W1, W1h, W1m, W1l);

  hipMemsetAsync(rowcnt, 0, (size_t)BN * 4, stream);

  // G1: P1raw = x @ W1  (split-3 MFMA; dis applied in K2)
  mgemm64s3<<<dim3(H_ / 64, BN / 64, 1), dim3(256), 0, stream>>>(
      xh, xm, xl, W1h, W1m, W1l, P1, H_, F_);

  // K1: degrees + bitmask + coalesced adj_bf (overwrites xm, dead after G1)
  k_degrees<<<dim3(BN), dim3(256), 0, stream>>>(adj, dis_bin, dr, dc, bm, adjBF);

  // K2: x1 + fused t (bitmask, wave scan)
  k_spmm_relu<<<dim3(BN), dim3(256), 0, stream>>>(bm, P1, dis_bin, b1, Watt, x1, t);

  // alpha + top-k cut/mask + S
  k_alpha<<<dim3(BN), dim3(256), 0, stream>>>(bm, dis_bin, t, batt, alpha);
  k_cutmask2<<<dim3(B_), dim3(1024), 0, stream>>>(alpha, nsent, nout, out_im, ca);
  k_build_S<<<dim3(BN), dim3(256), 0, stream>>>(adj, dr, dc, ca, out_S);

  // transposes: St, x1T  (adjT eliminated via M1^T formulation)
  k_convT<<<dim3(N_ / 32, N_ / 32, B_), dim3(256), 0, stream>>>(out_S, St, N_, N_, NN, NN);
  k_convT<<<dim3(H_ / 32, N_ / 32, B_), dim3(256), 0, stream>>>(x1, x1T, N_, H_, NH, NH);

  // G5: coarse_x = S^T @ x1 + fused cx_bf
  mgemm64<<<dim3(H_ / 64, N_ / 64, B_), dim3(256), 0, stream>>>(
      St, x1T, out_cx, H_, N_, NN, NH, NH, cx_bf);
  k_rowmean<H_><<<dim3(BN), dim3(256), 0, stream>>>(out_cx, out_xs0);

  // G6': M1^T = S^T @ adj^T = (adj @ S)^T   (A=St, Bt=adj_bf, bf16 out)
  mgemm<1><<<dim3(N_ / 128, N_ / 128, B_), dim3(256), 0, stream>>>(
      St, adjBF, M1t, N_, N_, N_, NN, NN, NN, N_, nullptr, nullptr, nullptr, nullptr);

  // G7': coarse_adj = floorq(S^T @ M1) + rowcnt + cbin(diag+1)
  mgemm<2><<<dim3(N_ / 128, N_ / 128, B_), dim3(256), 0, stream>>>(
      St, M1t, out_cadj, N_, N_, N_, NN, NN, NN, N_, nullptr, nullptr, rowcnt, cbin);

  // W2T  [F][H] bf16
  k_convT<<<dim3(F_ / 32, H_ / 32, 1), dim3(256), 0, stream>>>(W2, W2T, H_, F_, 0, 0);

  // G8' (transposed role): P2T[f][r] = f2b(rsqrt(1+cnt[r]) * (W2T[f] . cx_bf[r]))
  mgemm<5><<<dim3(BN / 128, F_ / 128, 1), dim3(256), 0, stream>>>(
      W2T, cx_bf, P2T, F_, BN, H_, 0, 0, 0, H_, rowcnt, nullptr, nullptr, nullptr);

  // G9: x2 = tanh(rsqrt(1+cnt[row]) * (cbin' @ P2) + b2)  (diag folded)
  mgemm<3><<<dim3(F_ / 128, N_ / 128, B_), dim3(256), 0, stream>>>(
      cbin, P2T, out_x2, N_, F_, N_, NN, N_, NF, (long)BN, rowcnt, b2,
      nullptr, nullptr);

  k_rowmean<F_><<<dim3(BN), dim3(256), 0, stream>>>(out_x2, out_xs1);
}

// Round 11
// 435.254 us; speedup vs baseline: 1.6445x; 1.0130x over previous
//
#include <hip/hip_runtime.h>

#define B_ 16
#define N_ 1024
#define F_ 768
#define H_ 128

typedef float f32x4 __attribute__((ext_vector_type(4)));
typedef short s16x8 __attribute__((ext_vector_type(8)));
typedef unsigned short u16;
typedef u16 u16x8 __attribute__((ext_vector_type(8)));
typedef u16 u16x4 __attribute__((ext_vector_type(4)));
typedef unsigned long long u64;

__device__ __forceinline__ u16 f2b(float f) {
  unsigned u = __float_as_uint(f);
  unsigned r = (u + 0x7FFFu + ((u >> 16) & 1u)) >> 16;
  return (u16)r;
}
__device__ __forceinline__ float b2f(u16 u) {
  return __uint_as_float(((unsigned)u) << 16);
}

__device__ __forceinline__ void gload16(const u16* g, u16* l) {
  __builtin_amdgcn_global_load_lds(
      (const __attribute__((address_space(1))) unsigned int*)g,
      (__attribute__((address_space(3))) unsigned int*)l, 16, 0, 0);
}

// ---------------------------------------------------------------------------
__device__ __forceinline__ float blockReduceSum256(float v) {
  __shared__ float red[4];
  #pragma unroll
  for (int o = 32; o > 0; o >>= 1) v += __shfl_down(v, o, 64);
  if ((threadIdx.x & 63) == 0) red[threadIdx.x >> 6] = v;
  __syncthreads();
  float r = red[0] + red[1] + red[2] + red[3];
  __syncthreads();
  return r;
}

// ---------------------------------------------------------------------------
// K1: degrees + bitmask + coalesced adj_bf (bf16, row-major) emission
// ---------------------------------------------------------------------------
__global__ __launch_bounds__(256) void k_degrees(
    const float* __restrict__ adj, float* __restrict__ dis_bin,
    float* __restrict__ dr, float* __restrict__ dc, u64* __restrict__ bm,
    u16* __restrict__ adj_bf) {
  long row = blockIdx.x;
  const float* a = adj + row * N_;
  u16* ab = adj_bf + row * N_;
  int tid = threadIdx.x;
  float cnt = 0.f, sw = 0.f;
  #pragma unroll
  for (int it = 0; it < 4; ++it) {
    int j = tid + it * 256;
    float v = a[j];
    ab[j] = f2b(v);
    bool nz = (v != 0.0f);
    u64 ball = __ballot(nz);
    if ((tid & 63) == 0) bm[row * 16 + it * 4 + (tid >> 6)] = ball;
    if (nz) { cnt += 1.0f; sw += v; }
  }
  __shared__ float r1[4], r2[4];
  #pragma unroll
  for (int o = 32; o > 0; o >>= 1) { cnt += __shfl_down(cnt, o, 64); sw += __shfl_down(sw, o, 64); }
  if ((tid & 63) == 0) { r1[tid >> 6] = cnt; r2[tid >> 6] = sw; }
  __syncthreads();
  if (tid == 0) {
    float c = r1[0] + r1[1] + r1[2] + r1[3];
    float s = r2[0] + r2[1] + r2[2] + r2[3];
    dis_bin[row] = rsqrtf(c + 1.0f);
    float d = rsqrtf(s + 1.0f);
    dc[row] = d;
    dr[row] = (s > 0.0f) ? d : 0.0f;
  }
}

// ---------------------------------------------------------------------------
// split f32 -> 3 bf16 planes
// ---------------------------------------------------------------------------
__global__ __launch_bounds__(256) void k_split3(
    const float* __restrict__ X, u16* __restrict__ Yh, u16* __restrict__ Ym,
    u16* __restrict__ Yl, long n4) {
  long i = (long)blockIdx.x * 256 + threadIdx.x;
  long stride = (long)gridDim.x * 256;
  for (; i < n4; i += stride) {
    f32x4 v = *(const f32x4*)(X + i * 4);
    u16x4 oh, om, ol;
    #pragma unroll
    for (int e = 0; e < 4; ++e) {
      float f = v[e];
      u16 h = f2b(f); float r1 = f - b2f(h);
      u16 m = f2b(r1); float r2 = r1 - b2f(m);
      u16 l = f2b(r2);
      oh[e] = h; om[e] = m; ol[e] = l;
    }
    *(u16x4*)(Yh + i * 4) = oh;
    *(u16x4*)(Ym + i * 4) = om;
    *(u16x4*)(Yl + i * 4) = ol;
  }
}

// transpose W1 [F][H] -> [H][F] with 3-way split
__global__ __launch_bounds__(256) void k_convT3(
    const float* __restrict__ X, u16* __restrict__ Yh, u16* __restrict__ Ym,
    u16* __restrict__ Yl) {
  __shared__ float tile[32][33];
  int tx = threadIdx.x & 31, ty = threadIdx.x >> 5;
  int r0 = blockIdx.y * 32, c0 = blockIdx.x * 32;
  #pragma unroll
  for (int i = 0; i < 4; ++i)
    tile[ty + i * 8][tx] = X[(long)(r0 + ty + i * 8) * H_ + (c0 + tx)];
  __syncthreads();
  #pragma unroll
  for (int i = 0; i < 4; ++i) {
    float v = tile[tx][ty + i * 8];
    long o = (long)(c0 + ty + i * 8) * F_ + (r0 + tx);
    u16 h = f2b(v); float r1 = v - b2f(h);
    u16 m = f2b(r1); float r2 = r1 - b2f(m);
    u16 l = f2b(r2);
    Yh[o] = h; Ym[o] = m; Yl[o] = l;
  }
}

// ---------------------------------------------------------------------------
// mgemmW: 128(M) x 64(N) tile, BK=32, gload_lds staging, NPLANES split planes.
// C = sum over product set of (Ap @ Bq^T); NPLANES=3 uses {hh,hm,mh,mm,hl,lh}.
// 4 waves (2x2): wave covers 64x32. B rows stride = K.
// MODE 0: f32 C | MODE 1: f32 C + bf16 mirror Cbf
// ---------------------------------------------------------------------------
template<int NPLANES, int MODE>
__global__ __launch_bounds__(256) void mgemmW(
    const u16* __restrict__ A0, const u16* __restrict__ A1, const u16* __restrict__ A2,
    const u16* __restrict__ B0, const u16* __restrict__ B1, const u16* __restrict__ B2,
    float* __restrict__ C, int N, int K, long sA, long sB, long sC,
    u16* __restrict__ Cbf) {
  int bz = blockIdx.z;
  int m0 = blockIdx.y * 128, n0 = blockIdx.x * 64;
  __shared__ __align__(16) u16 As[NPLANES][128 * 32];
  __shared__ __align__(16) u16 Bs[NPLANES][64 * 32];
  int tid = threadIdx.x;
  int lane = tid & 63, wave = tid >> 6;
  int wr = wave >> 1, wc = wave & 1;
  int kg = lane >> 4, r16 = lane & 15;
  const u16* Aps[3] = {A0, A1, A2};
  const u16* Bps[3] = {B0, B1, B2};
  const u16* ga[NPLANES];
  const u16* gb[NPLANES];
  #pragma unroll
  for (int p2 = 0; p2 < NPLANES; ++p2) {
    ga[p2] = Aps[p2] + (long)bz * sA + (long)(m0 + (tid >> 2)) * K + (tid & 3) * 8;
    gb[p2] = Bps[p2] + (long)bz * sB + (long)(n0 + (tid >> 2)) * K + (tid & 3) * 8;
  }
  f32x4 acc[4][2] = {};

  for (int k0 = 0; k0 < K; k0 += 32) {
    #pragma unroll
    for (int p2 = 0; p2 < NPLANES; ++p2) {
      gload16(ga[p2] + k0, &As[p2][tid * 8]);
      gload16(ga[p2] + (long)64 * K + k0, &As[p2][2048 + tid * 8]);
      gload16(gb[p2] + k0, &Bs[p2][tid * 8]);
    }
    __syncthreads();
    s16x8 af[NPLANES][4], bf[NPLANES][2];
    #pragma unroll
    for (int p2 = 0; p2 < NPLANES; ++p2) {
      #pragma unroll
      for (int m = 0; m < 4; ++m)
        af[p2][m] = *(const s16x8*)(&As[p2][(wr * 64 + m * 16 + r16) * 32 + kg * 8]);
      #pragma unroll
      for (int n = 0; n < 2; ++n)
        bf[p2][n] = *(const s16x8*)(&Bs[p2][(wc * 32 + n * 16 + r16) * 32 + kg * 8]);
    }
    #pragma unroll
    for (int m = 0; m < 4; ++m)
      #pragma unroll
      for (int n = 0; n < 2; ++n) {
        acc[m][n] = __builtin_amdgcn_mfma_f32_16x16x32_bf16(af[0][m], bf[0][n], acc[m][n], 0, 0, 0);
        if constexpr (NPLANES == 3) {
          acc[m][n] = __builtin_amdgcn_mfma_f32_16x16x32_bf16(af[0][m], bf[1][n], acc[m][n], 0, 0, 0);
          acc[m][n] = __builtin_amdgcn_mfma_f32_16x16x32_bf16(af[1][m], bf[0][n], acc[m][n], 0, 0, 0);
          acc[m][n] = __builtin_amdgcn_mfma_f32_16x16x32_bf16(af[1][m], bf[1][n], acc[m][n], 0, 0, 0);
          acc[m][n] = __builtin_amdgcn_mfma_f32_16x16x32_bf16(af[0][m], bf[2][n], acc[m][n], 0, 0, 0);
          acc[m][n] = __builtin_amdgcn_mfma_f32_16x16x32_bf16(af[2][m], bf[0][n], acc[m][n], 0, 0, 0);
        }
      }
    __syncthreads();
  }

  #pragma unroll
  for (int m = 0; m < 4; ++m)
    #pragma unroll
    for (int r = 0; r < 4; ++r) {
      int row = m0 + wr * 64 + m * 16 + kg * 4 + r;
      #pragma unroll
      for (int n = 0; n < 2; ++n) {
        int col = n0 + wc * 32 + n * 16 + r16;
        long cidx = (long)bz * sC + (long)row * N + col;
        float v = acc[m][n][r];
        C[cidx] = v;
        if constexpr (MODE == 1) Cbf[cidx] = f2b(v);
      }
    }
}

// ---------------------------------------------------------------------------
// K2: x1 = relu(dis_i*(sum_{bit j} dis_j*P1_j + dis_i*P1_i) + b1)
// bitmask-driven; wave-level scan; fused t[row] = x1_row . Watt
// ---------------------------------------------------------------------------
__global__ __launch_bounds__(256) void k_spmm_relu(
    const u64* __restrict__ bm, const float* __restrict__ P1,
    const float* __restrict__ dis_bin, const float* __restrict__ b1,
    const float* __restrict__ Watt, float* __restrict__ x1,
    float* __restrict__ t) {
  long row = blockIdx.x;
  int b = (int)(row >> 10), i = (int)(row & 1023);
  const float* Pb = P1 + (long)b * (long)N_ * H_;
  const float* db = dis_bin + (long)b * N_;
  __shared__ int idxs[N_];
  __shared__ int wtot[4];
  __shared__ float accs[H_];
  int tid = threadIdx.x;
  int wid = tid >> 6, lane = tid & 63;
  int base = tid * 4;
  u64 word = bm[row * 16 + (tid >> 4)];
  int sh = base & 63;
  int f0 = (int)((word >> sh) & 1), f1 = (int)((word >> (sh + 1)) & 1);
  int f2 = (int)((word >> (sh + 2)) & 1), f3 = (int)((word >> (sh + 3)) & 1);
  int c0 = f0 + f1 + f2 + f3;
  int inc = c0;
  #pragma unroll
  for (int o = 1; o < 64; o <<= 1) {
    int v = __shfl_up(inc, o, 64);
    if (lane >= o) inc += v;
  }
  if (lane == 63) wtot[wid] = inc;
  __syncthreads();
  int wbase = 0;
  #pragma unroll
  for (int w = 0; w < 4; ++w) wbase += (w < wid) ? wtot[w] : 0;
  int pos = wbase + inc - c0;
  int n = wtot[0] + wtot[1] + wtot[2] + wtot[3];
  if (f0) idxs[pos++] = base;
  if (f1) idxs[pos++] = base + 1;
  if (f2) idxs[pos++] = base + 2;
  if (f3) idxs[pos++] = base + 3;
  __syncthreads();
  int c = tid & 127, team = tid >> 7;
  float acc = 0.f;
  for (int u = team; u < n; u += 2) {
    int j = idxs[u];
    acc += db[j] * Pb[(long)j * H_ + c];
  }
  if (team == 1) accs[c] = acc;
  __syncthreads();
  float v = 0.f;
  if (team == 0) {
    float di = db[i];
    float tot = acc + accs[c] + di * Pb[(long)i * H_ + c];
    v = fmaxf(di * tot + b1[c], 0.0f);
    x1[row * H_ + c] = v;
  }
  __syncthreads();
  float prod = (team == 0) ? v * Watt[c] : 0.f;
  float s = blockReduceSum256(prod);
  if (tid == 0) t[row] = s;
}

// ---------------------------------------------------------------------------
// K5: alpha (bitmask-driven)
// ---------------------------------------------------------------------------
__global__ __launch_bounds__(256) void k_alpha(
    const u64* __restrict__ bm, const float* __restrict__ dis_bin,
    const float* __restrict__ t, const float* __restrict__ batt,
    float* __restrict__ alpha) {
  long row = blockIdx.x;
  int b = (int)(row >> 10), i = (int)(row & 1023);
  const float* db = dis_bin + (long)b * N_;
  const float* tb = t + (long)b * N_;
  int tid = threadIdx.x;
  float s = 0.f;
  #pragma unroll
  for (int it = 0; it < 4; ++it) {
    int j = tid + it * 256;
    u64 word = bm[row * 16 + (j >> 6)];
    if ((word >> (j & 63)) & 1) s += db[j] * tb[j];
  }
  s = blockReduceSum256(s);
  if (tid == 0) {
    float di = db[i];
    float pre = di * (s + di * tb[i]) + batt[0];
    float z = pre * pre;
    alpha[row] = 1.0f / (1.0f + expf(-z));
  }
}

// ---------------------------------------------------------------------------
// K6: top-k cut + mask (exact stable-sort semantics via composite key)
// ---------------------------------------------------------------------------
__global__ __launch_bounds__(1024) void k_cutmask2(
    const float* __restrict__ alpha, const int* __restrict__ num_sent,
    const int* __restrict__ nout, float* __restrict__ index_mask,
    float* __restrict__ ca) {
  int b = blockIdx.x, tid = threadIdx.x;
  __shared__ u64 keys[N_];
  __shared__ u64 red[N_];
  int ns = num_sent[b];
  float av = alpha[(long)b * N_ + tid];
  unsigned bits = __float_as_uint(av);
  u64 keyFull = ((u64)bits << 32) | (u64)(0xFFFFFFFFu - (unsigned)tid);
  keys[tid] = (tid < ns) ? keyFull : 0ULL;
  __syncthreads();
  int k = nout[0];
  u64 cutkey = 0;
  for (int r = 0; r < k; ++r) {
    red[tid] = keys[tid];
    __syncthreads();
    for (int off = 512; off > 0; off >>= 1) {
      if (tid < off) { u64 o = red[tid + off]; if (o > red[tid]) red[tid] = o; }
      __syncthreads();
    }
    u64 mx = red[0];
    __syncthreads();
    if (r == k - 1) cutkey = mx;
    else if (keys[tid] == mx) keys[tid] = 0ULL;
    __syncthreads();
  }
  float cutalpha = __uint_as_float((unsigned)(cutkey >> 32));
  index_mask[(long)b * N_ + tid] = (keyFull >= cutkey) ? 1.0f : 0.0f;
  ca[(long)b * N_ + tid] = fmaxf(av + 1e-7f - cutalpha, 0.0f);
}

// ---------------------------------------------------------------------------
// K7: S build + L1 row-normalize (reads bf16 adj; register-resident row)
// ---------------------------------------------------------------------------
__global__ __launch_bounds__(256) void k_build_S(
    const u16* __restrict__ abf, const float* __restrict__ dr,
    const float* __restrict__ dc, const float* __restrict__ ca,
    float* __restrict__ S) {
  long row = blockIdx.x;
  int b = (int)(row >> 10), i = (int)(row & 1023);
  const u16* a = abf + row * N_;
  const float* dcb = dc + (long)b * N_;
  const float* cab = ca + (long)b * N_;
  float dri = dr[row];
  int tid = threadIdx.x;
  u16x4 av4 = *(const u16x4*)(a + tid * 4);
  f32x4 dc4 = *(const f32x4*)(dcb + tid * 4);
  f32x4 ca4 = *(const f32x4*)(cab + tid * 4);
  float ls = 0.f;
  f32x4 pv;
  #pragma unroll
  for (int e = 0; e < 4; ++e) {
    int j = tid * 4 + e;
    float avv = b2f(av4[e]) + ((j == i) ? 1.0f : 0.0f);
    float v = dri * avv * dc4[e] * ca4[e];
    pv[e] = v;
    ls += v;
  }
  float sum = blockReduceSum256(ls);
  float denom = fmaxf(sum, 1e-12f);
  f32x4 out;
  #pragma unroll
  for (int e = 0; e < 4; ++e) out[e] = pv[e] / denom;
  *(f32x4*)(&S[row * N_ + tid * 4]) = out;
}

// ---------------------------------------------------------------------------
// Big MFMA GEMM: 128x128 tile, BK=32, global_load_lds staging, XCD swizzle.
// B-operand rows (length K) at stride ldb (batch offset sB).
// MODE 1: bf16 C | 2: floorq + rowcnt + cbin(diag+1) |
// 3: f32 tanh(rsqrt(1+cnt[row])*acc + bias[col]) |
// 5: bf16 f2b(rsqrt(1+cnt[col])*acc)
// ---------------------------------------------------------------------------
template<int MODE>
__global__ __launch_bounds__(256) void mgemm(
    const u16* __restrict__ A, const u16* __restrict__ Bt, void* __restrict__ Cv,
    int M, int N, int K, long sA, long sB, long sC, long ldb,
    const int* __restrict__ cnt, const float* __restrict__ bias,
    int* __restrict__ rowcnt, u16* __restrict__ cbin) {
  // XCD-aware bijective chunked remap (total blocks divisible by 8)
  int gx = gridDim.x, gy = gridDim.y;
  int lin = (blockIdx.z * gy + blockIdx.y) * gx + blockIdx.x;
  int total = gx * gy * gridDim.z;
  int chunk = total >> 3;
  int swz = (lin & 7) * chunk + (lin >> 3);
  int bx = swz % gx; int t2 = swz / gx; int by = t2 % gy; int bz = t2 / gy;

  int m0 = by * 128, n0 = bx * 128;
  const u16* Ab = A + (long)bz * sA + (long)m0 * K;
  const u16* Bb = Bt + (long)bz * sB + (long)n0 * ldb;
  __shared__ __align__(16) u16 As[128 * 32];
  __shared__ __align__(16) u16 Bs[128 * 32];
  int tid = threadIdx.x;
  int lane = tid & 63, wave = tid >> 6;
  int wr = wave >> 1, wc = wave & 1;
  int kg = lane >> 4, r16 = lane & 15;
  const u16* ga = Ab + (long)(tid >> 2) * K + (tid & 3) * 8;
  const u16* gb = Bb + (long)(tid >> 2) * ldb + (tid & 3) * 8;
  f32x4 acc[4][4] = {};

  for (int k0 = 0; k0 < K; k0 += 32) {
    gload16(ga + k0, &As[tid * 8]);
    gload16(ga + (long)64 * K + k0, &As[2048 + tid * 8]);
    gload16(gb + k0, &Bs[tid * 8]);
    gload16(gb + (long)64 * ldb + k0, &Bs[2048 + tid * 8]);
    __syncthreads();
    s16x8 af[4], bfr[4];
    #pragma unroll
    for (int m = 0; m < 4; ++m)
      af[m] = *(const s16x8*)(&As[(wr * 64 + m * 16 + r16) * 32 + kg * 8]);
    #pragma unroll
    for (int n = 0; n < 4; ++n)
      bfr[n] = *(const s16x8*)(&Bs[(wc * 64 + n * 16 + r16) * 32 + kg * 8]);
    #pragma unroll
    for (int m = 0; m < 4; ++m)
      #pragma unroll
      for (int n = 0; n < 4; ++n)
        acc[m][n] = __builtin_amdgcn_mfma_f32_16x16x32_bf16(af[m], bfr[n], acc[m][n], 0, 0, 0);
    __syncthreads();
  }

  if constexpr (MODE == 2) {
    int* cntl = (int*)As;
    if (tid < 128) cntl[tid] = 0;
    __syncthreads();
    #pragma unroll
    for (int m = 0; m < 4; ++m) {
      #pragma unroll
      for (int r = 0; r < 4; ++r) {
        int lrow = wr * 64 + m * 16 + kg * 4 + r;
        int row = m0 + lrow;
        int nz = 0;
        #pragma unroll
        for (int n = 0; n < 4; ++n) {
          int col = n0 + wc * 64 + n * 16 + r16;
          float q = floorf(acc[m][n][r] * 10000.0f) / 10000.0f;
          long cidx = (long)bz * sC + (long)row * N + col;
          ((float*)Cv)[cidx] = q;
          bool qnz = (q != 0.0f);
          u16 bv;
          if (row == col) bv = qnz ? (u16)0x4000 : (u16)0x3F80;  // bin+I diag
          else            bv = qnz ? (u16)0x3F80 : (u16)0;
          cbin[cidx] = bv;
          nz += qnz ? 1 : 0;
        }
        atomicAdd(&cntl[lrow], nz);
      }
    }
    __syncthreads();
    if (tid < 128) atomicAdd(&rowcnt[(long)bz * N_ + m0 + tid], cntl[tid]);
    return;
  }

  #pragma unroll
  for (int m = 0; m < 4; ++m) {
    #pragma unroll
    for (int r = 0; r < 4; ++r) {
      int row = m0 + wr * 64 + m * 16 + kg * 4 + r;
      float sc = 0.f;
      if constexpr (MODE == 3)
        sc = rsqrtf(1.0f + (float)cnt[(long)bz * N_ + row]);
      #pragma unroll
      for (int n = 0; n < 4; ++n) {
        int col = n0 + wc * 64 + n * 16 + r16;
        float v = acc[m][n][r];
        long cidx = (long)bz * sC + (long)row * N + col;
        if constexpr (MODE == 1) {
          ((u16*)Cv)[cidx] = f2b(v);
        } else if constexpr (MODE == 3) {
          ((float*)Cv)[cidx] = tanhf(sc * v + bias[col]);
        } else if constexpr (MODE == 5) {
          float scc = rsqrtf(1.0f + (float)cnt[col]);
          ((u16*)Cv)[cidx] = f2b(scc * v);
        } else {
          ((float*)Cv)[cidx] = v;
        }
      }
    }
  }
}

// ---------------------------------------------------------------------------
// transpose-convert: X[b][R][C] f32 -> Y[b][C][R] bf16 (LDS-staged, coalesced)
// ---------------------------------------------------------------------------
__global__ __launch_bounds__(256) void k_convT(
    const float* __restrict__ X, u16* __restrict__ Y, int R, int C,
    long sX, long sY) {
  __shared__ float tile[32][33];
  const float* Xb = X + (long)blockIdx.z * sX;
  u16* Yb = Y + (long)blockIdx.z * sY;
  int tx = threadIdx.x & 31, ty = threadIdx.x >> 5;
  int r0 = blockIdx.y * 32, c0 = blockIdx.x * 32;
  #pragma unroll
  for (int i = 0; i < 4; ++i)
    tile[ty + i * 8][tx] = Xb[(long)(r0 + ty + i * 8) * C + (c0 + tx)];
  __syncthreads();
  #pragma unroll
  for (int i = 0; i < 4; ++i)
    Yb[(long)(c0 + ty + i * 8) * R + (r0 + tx)] = f2b(tile[tx][ty + i * 8]);
}

// ---------------------------------------------------------------------------
template<int W>
__global__ __launch_bounds__(256) void k_rowmean(
    const float* __restrict__ X, float* __restrict__ out) {
  long row = blockIdx.x;
  float s = 0.f;
  for (int j = threadIdx.x; j < W; j += 256) s += X[row * W + j];
  float r = blockReduceSum256(s);
  if (threadIdx.x == 0) out[row] = r / (float)W;
}

// ---------------------------------------------------------------------------
extern "C" void kernel_launch(void* const* d_in, const int* in_sizes, int n_in,
                              void* d_out, int out_size, void* d_ws, size_t ws_size,
                              hipStream_t stream) {
  const float* x     = (const float*)d_in[0];
  const float* adj   = (const float*)d_in[1];
  const int*   nsent = (const int*)d_in[2];
  const float* W1    = (const float*)d_in[3];
  const float* b1    = (const float*)d_in[4];
  const float* Watt  = (const float*)d_in[5];
  const float* batt  = (const float*)d_in[6];
  const float* W2    = (const float*)d_in[7];
  const float* b2    = (const float*)d_in[8];
  const int*   nout  = (const int*)d_in[9];

  const long NN = (long)N_ * N_;
  const long NH = (long)N_ * H_;
  const long NF = (long)N_ * F_;
  const int BN = B_ * N_;

  // output layout (flat concat, f32)
  float* out_x2   = (float*)d_out;
  float* out_cx   = out_x2 + (long)B_ * NF;
  float* out_cadj = out_cx + (long)B_ * NH;
  float* out_S    = out_cadj + (long)B_ * NN;
  float* out_im   = out_S + (long)B_ * NN;
  float* out_xs0  = out_im + BN;
  float* out_xs1  = out_xs0 + BN;

  // workspace (~142MB, proven scale)
  char* wsb = (char*)d_ws;
  float* P1      = (float*)wsb;
  float* x1      = P1 + (long)B_ * NH;
  float* t       = x1 + (long)B_ * NH;
  float* alpha   = t + BN;
  float* dis_bin = alpha + BN;
  float* dr      = dis_bin + BN;
  float* dc      = dr + BN;
  float* ca      = dc + BN;
  int*   rowcnt  = (int*)(ca + BN);
  u64*   bm      = (u64*)(rowcnt + BN);       // 2MB bitmask
  char*  p       = (char*)(bm + (long)BN * 16);
  p = (char*)(((size_t)p + 255) & ~(size_t)255);
  u16* W1h   = (u16*)p;  p += (long)H_ * F_ * 2;
  u16* W1m   = (u16*)p;  p += (long)H_ * F_ * 2;
  u16* W1l   = (u16*)p;  p += (long)H_ * F_ * 2;
  u16* W2T   = (u16*)p;  p += (long)H_ * F_ * 2;
  u16* PT    = (u16*)p;  p += (long)B_ * NH * 2;   // x1T
  u16* St    = (u16*)p;  p += (long)B_ * NN * 2;   // xh -> St -> P2T
  u16* adjBF = (u16*)p;  p += (long)B_ * NN * 2;   // xm -> adj_bf -> cbin
  u16* xl3   = (u16*)p;                             // xl plane (24MB)
  u16* xh    = St;
  u16* xm    = adjBF;
  u16* xl    = xl3;
  u16* cx_bf = (u16*)P1;       // P1 dead after spmm
  u16* x1T   = PT;
  u16* cbin  = adjBF;          // adj_bf dead after G6'
  u16* P2T   = St;             // St dead after G7'
  u16* M1t   = (u16*)out_x2;   // scratch in unwritten output region (32MB)

  // split x and W1 into 3 bf16 planes
  k_split3<<<dim3(2048), dim3(256), 0, stream>>>(x, xh, xm, xl, (long)B_ * NF / 4);
  k_convT3<<<dim3(H_ / 32, F_ / 32, 1), dim3(256), 0, stream>>>(W1, W1h, W1m, W1l);

  hipMemsetAsync(rowcnt, 0, (size_t)BN * 4, stream);

  // G1: P1raw = x @ W1  (split-3, gload-staged 128x64 tile; dis applied in K2)
  mgemmW<3, 0><<<dim3(H_ / 64, BN / 128, 1), dim3(256), 0, stream>>>(
      xh, xm, xl, W1h, W1m, W1l, P1, H_, F_, 0, 0, 0, nullptr);

  // K1: degrees + bitmask + coalesced adj_bf (overwrites xm, dead after G1)
  k_degrees<<<dim3(BN), dim3(256), 0, stream>>>(adj, dis_bin, dr, dc, bm, adjBF);

  // K2: x1 + fused t (bitmask, wave scan)
  k_spmm_relu<<<dim3(BN), dim3(256), 0, stream>>>(bm, P1, dis_bin, b1, Watt, x1, t);

  // alpha + top-k cut/mask + S (S from bf16 adj)
  k_alpha<<<dim3(BN), dim3(256), 0, stream>>>(bm, dis_bin, t, batt, alpha);
  k_cutmask2<<<dim3(B_), dim3(1024), 0, stream>>>(alpha, nsent, nout, out_im, ca);
  k_build_S<<<dim3(BN), dim3(256), 0, stream>>>(adjBF, dr, dc, ca, out_S);

  // transposes: St, x1T
  k_convT<<<dim3(N_ / 32, N_ / 32, B_), dim3(256), 0, stream>>>(out_S, St, N_, N_, NN, NN);
  k_convT<<<dim3(H_ / 32, N_ / 32, B_), dim3(256), 0, stream>>>(x1, x1T, N_, H_, NH, NH);

  // G5: coarse_x = S^T @ x1 + fused cx_bf  (gload-staged 128x64)
  mgemmW<1, 1><<<dim3(H_ / 64, N_ / 128, B_), dim3(256), 0, stream>>>(
      St, St, St, x1T, x1T, x1T, out_cx, H_, N_, NN, NH, NH, cx_bf);
  k_rowmean<H_><<<dim3(BN), dim3(256), 0, stream>>>(out_cx, out_xs0);

  // G6': M1^T = S^T @ adj^T = (adj @ S)^T   (A=St, Bt=adj_bf, bf16 out)
  mgemm<1><<<dim3(N_ / 128, N_ / 128, B_), dim3(256), 0, stream>>>(
      St, adjBF, M1t, N_, N_, N_, NN, NN, NN, N_, nullptr, nullptr, nullptr, nullptr);

  // G7': coarse_adj = floorq(S^T @ M1) + rowcnt + cbin(diag+1)
  mgemm<2><<<dim3(N_ / 128, N_ / 128, B_), dim3(256), 0, stream>>>(
      St, M1t, out_cadj, N_, N_, N_, NN, NN, NN, N_, nullptr, nullptr, rowcnt, cbin);

  // W2T  [F][H] bf16
  k_convT<<<dim3(F_ / 32, H_ / 32, 1), dim3(256), 0, stream>>>(W2, W2T, H_, F_, 0, 0);

  // G8' (transposed role): P2T[f][r] = f2b(rsqrt(1+cnt[r]) * (W2T[f] . cx_bf[r]))
  mgemm<5><<<dim3(BN / 128, F_ / 128, 1), dim3(256), 0, stream>>>(
      W2T, cx_bf, P2T, F_, BN, H_, 0, 0, 0, H_, rowcnt, nullptr, nullptr, nullptr);

  // G9: x2 = tanh(rsqrt(1+cnt[row]) * (cbin' @ P2) + b2)  (diag folded)
  mgemm<3><<<dim3(F_ / 128, N_ / 128, B_), dim3(256), 0, stream>>>(
      cbin, P2T, out_x2, N_, F_, N_, NN, N_, NF, (long)BN, rowcnt, b2,
      nullptr, nullptr);

  k_rowmean<F_><<<dim3(BN), dim3(256), 0, stream>>>(out_x2, out_xs1);
}

// Round 12
// 424.171 us; speedup vs baseline: 1.6874x; 1.0261x over previous
//
#include <hip/hip_runtime.h>

#define B_ 16
#define N_ 1024
#define F_ 768
#define H_ 128

typedef float f32x4 __attribute__((ext_vector_type(4)));
typedef short s16x8 __attribute__((ext_vector_type(8)));
typedef unsigned short u16;
typedef u16 u16x8 __attribute__((ext_vector_type(8)));
typedef u16 u16x4 __attribute__((ext_vector_type(4)));
typedef unsigned long long u64;

__device__ __forceinline__ u16 f2b(float f) {
  unsigned u = __float_as_uint(f);
  unsigned r = (u + 0x7FFFu + ((u >> 16) & 1u)) >> 16;
  return (u16)r;
}
__device__ __forceinline__ float b2f(u16 u) {
  return __uint_as_float(((unsigned)u) << 16);
}

__device__ __forceinline__ void gload16(const u16* g, u16* l) {
  __builtin_amdgcn_global_load_lds(
      (const __attribute__((address_space(1))) unsigned int*)g,
      (__attribute__((address_space(3))) unsigned int*)l, 16, 0, 0);
}

// fast tanh: (e^{2z}-1)/(e^{2z}+1), z clamped to +-10 (err ~1e-6)
__device__ __forceinline__ float ftanh(float z) {
  z = fminf(fmaxf(z, -10.0f), 10.0f);
  float e = __expf(2.0f * z);
  return (e - 1.0f) / (e + 1.0f);
}

// ---------------------------------------------------------------------------
__device__ __forceinline__ float blockReduceSum256(float v) {
  __shared__ float red[4];
  #pragma unroll
  for (int o = 32; o > 0; o >>= 1) v += __shfl_down(v, o, 64);
  if ((threadIdx.x & 63) == 0) red[threadIdx.x >> 6] = v;
  __syncthreads();
  float r = red[0] + red[1] + red[2] + red[3];
  __syncthreads();
  return r;
}

// ---------------------------------------------------------------------------
// K1: degrees + bitmask + coalesced adj_bf emission + rowcnt zeroing
// ---------------------------------------------------------------------------
__global__ __launch_bounds__(256) void k_degrees(
    const float* __restrict__ adj, float* __restrict__ dis_bin,
    float* __restrict__ dr, float* __restrict__ dc, u64* __restrict__ bm,
    u16* __restrict__ adj_bf, int* __restrict__ rowcnt) {
  long row = blockIdx.x;
  const float* a = adj + row * N_;
  u16* ab = adj_bf + row * N_;
  int tid = threadIdx.x;
  float cnt = 0.f, sw = 0.f;
  #pragma unroll
  for (int it = 0; it < 4; ++it) {
    int j = tid + it * 256;
    float v = a[j];
    ab[j] = f2b(v);
    bool nz = (v != 0.0f);
    u64 ball = __ballot(nz);
    if ((tid & 63) == 0) bm[row * 16 + it * 4 + (tid >> 6)] = ball;
    if (nz) { cnt += 1.0f; sw += v; }
  }
  __shared__ float r1[4], r2[4];
  #pragma unroll
  for (int o = 32; o > 0; o >>= 1) { cnt += __shfl_down(cnt, o, 64); sw += __shfl_down(sw, o, 64); }
  if ((tid & 63) == 0) { r1[tid >> 6] = cnt; r2[tid >> 6] = sw; }
  __syncthreads();
  if (tid == 0) {
    float c = r1[0] + r1[1] + r1[2] + r1[3];
    float s = r2[0] + r2[1] + r2[2] + r2[3];
    dis_bin[row] = rsqrtf(c + 1.0f);
    float d = rsqrtf(s + 1.0f);
    dc[row] = d;
    dr[row] = (s > 0.0f) ? d : 0.0f;
    rowcnt[row] = 0;
  }
}

// ---------------------------------------------------------------------------
// K0: merged prep — split x into 3 bf16 planes (blocks 0..2047) and
// transpose-split W1 [F][H] -> [H][F] (blocks 2048..2143)
// ---------------------------------------------------------------------------
__global__ __launch_bounds__(256) void k_prep(
    const float* __restrict__ X, u16* __restrict__ Yh, u16* __restrict__ Ym,
    u16* __restrict__ Yl, long n4,
    const float* __restrict__ W1, u16* __restrict__ W1h,
    u16* __restrict__ W1m, u16* __restrict__ W1l) {
  __shared__ float tile[32][33];
  if (blockIdx.x < 2048) {
    long i = (long)blockIdx.x * 256 + threadIdx.x;
    long stride = 2048L * 256;
    for (; i < n4; i += stride) {
      f32x4 v = *(const f32x4*)(X + i * 4);
      u16x4 oh, om, ol;
      #pragma unroll
      for (int e = 0; e < 4; ++e) {
        float f = v[e];
        u16 h = f2b(f); float r1 = f - b2f(h);
        u16 m = f2b(r1); float r2 = r1 - b2f(m);
        u16 l = f2b(r2);
        oh[e] = h; om[e] = m; ol[e] = l;
      }
      *(u16x4*)(Yh + i * 4) = oh;
      *(u16x4*)(Ym + i * 4) = om;
      *(u16x4*)(Yl + i * 4) = ol;
    }
  } else {
    int bid = blockIdx.x - 2048;       // 96 blocks: (H/32)=4 x (F/32)=24
    int bx = bid & 3, by = bid >> 2;
    int tx = threadIdx.x & 31, ty = threadIdx.x >> 5;
    int r0 = by * 32, c0 = bx * 32;    // r: F dim, c: H dim
    #pragma unroll
    for (int i = 0; i < 4; ++i)
      tile[ty + i * 8][tx] = W1[(long)(r0 + ty + i * 8) * H_ + (c0 + tx)];
    __syncthreads();
    #pragma unroll
    for (int i = 0; i < 4; ++i) {
      float v = tile[tx][ty + i * 8];
      long o = (long)(c0 + ty + i * 8) * F_ + (r0 + tx);
      u16 h = f2b(v); float r1 = v - b2f(h);
      u16 m = f2b(r1); float r2 = r1 - b2f(m);
      u16 l = f2b(r2);
      W1h[o] = h; W1m[o] = m; W1l[o] = l;
    }
  }
}

// ---------------------------------------------------------------------------
// mgemmW: 128(M) x 64(N) tile, BK=32, gload_lds staging, NPLANES split planes.
// MODE 0: f32 C | MODE 1: f32 C + bf16 mirror Cbf + xs row-mean atomics
// ---------------------------------------------------------------------------
template<int NPLANES, int MODE>
__global__ __launch_bounds__(256) void mgemmW(
    const u16* __restrict__ A0, const u16* __restrict__ A1, const u16* __restrict__ A2,
    const u16* __restrict__ B0, const u16* __restrict__ B1, const u16* __restrict__ B2,
    float* __restrict__ C, int N, int K, long sA, long sB, long sC,
    u16* __restrict__ Cbf, float* __restrict__ xsum) {
  int bz = blockIdx.z;
  int m0 = blockIdx.y * 128, n0 = blockIdx.x * 64;
  __shared__ __align__(16) u16 As[NPLANES][128 * 32];
  __shared__ __align__(16) u16 Bs[NPLANES][64 * 32];
  int tid = threadIdx.x;
  int lane = tid & 63, wave = tid >> 6;
  int wr = wave >> 1, wc = wave & 1;
  int kg = lane >> 4, r16 = lane & 15;
  const u16* Aps[3] = {A0, A1, A2};
  const u16* Bps[3] = {B0, B1, B2};
  const u16* ga[NPLANES];
  const u16* gb[NPLANES];
  #pragma unroll
  for (int p2 = 0; p2 < NPLANES; ++p2) {
    ga[p2] = Aps[p2] + (long)bz * sA + (long)(m0 + (tid >> 2)) * K + (tid & 3) * 8;
    gb[p2] = Bps[p2] + (long)bz * sB + (long)(n0 + (tid >> 2)) * K + (tid & 3) * 8;
  }
  f32x4 acc[4][2] = {};

  for (int k0 = 0; k0 < K; k0 += 32) {
    #pragma unroll
    for (int p2 = 0; p2 < NPLANES; ++p2) {
      gload16(ga[p2] + k0, &As[p2][tid * 8]);
      gload16(ga[p2] + (long)64 * K + k0, &As[p2][2048 + tid * 8]);
      gload16(gb[p2] + k0, &Bs[p2][tid * 8]);
    }
    __syncthreads();
    s16x8 af[NPLANES][4], bf[NPLANES][2];
    #pragma unroll
    for (int p2 = 0; p2 < NPLANES; ++p2) {
      #pragma unroll
      for (int m = 0; m < 4; ++m)
        af[p2][m] = *(const s16x8*)(&As[p2][(wr * 64 + m * 16 + r16) * 32 + kg * 8]);
      #pragma unroll
      for (int n = 0; n < 2; ++n)
        bf[p2][n] = *(const s16x8*)(&Bs[p2][(wc * 32 + n * 16 + r16) * 32 + kg * 8]);
    }
    #pragma unroll
    for (int m = 0; m < 4; ++m)
      #pragma unroll
      for (int n = 0; n < 2; ++n) {
        acc[m][n] = __builtin_amdgcn_mfma_f32_16x16x32_bf16(af[0][m], bf[0][n], acc[m][n], 0, 0, 0);
        if constexpr (NPLANES == 3) {
          acc[m][n] = __builtin_amdgcn_mfma_f32_16x16x32_bf16(af[0][m], bf[1][n], acc[m][n], 0, 0, 0);
          acc[m][n] = __builtin_amdgcn_mfma_f32_16x16x32_bf16(af[1][m], bf[0][n], acc[m][n], 0, 0, 0);
          acc[m][n] = __builtin_amdgcn_mfma_f32_16x16x32_bf16(af[1][m], bf[1][n], acc[m][n], 0, 0, 0);
          acc[m][n] = __builtin_amdgcn_mfma_f32_16x16x32_bf16(af[0][m], bf[2][n], acc[m][n], 0, 0, 0);
          acc[m][n] = __builtin_amdgcn_mfma_f32_16x16x32_bf16(af[2][m], bf[0][n], acc[m][n], 0, 0, 0);
        }
      }
    __syncthreads();
  }

  #pragma unroll
  for (int m = 0; m < 4; ++m)
    #pragma unroll
    for (int r = 0; r < 4; ++r) {
      int row = m0 + wr * 64 + m * 16 + kg * 4 + r;
      float part = 0.f;
      #pragma unroll
      for (int n = 0; n < 2; ++n) {
        int col = n0 + wc * 32 + n * 16 + r16;
        long cidx = (long)bz * sC + (long)row * N + col;
        float v = acc[m][n][r];
        C[cidx] = v;
        if constexpr (MODE == 1) { Cbf[cidx] = f2b(v); part += v; }
      }
      if constexpr (MODE == 1) {
        #pragma unroll
        for (int o2 = 1; o2 < 16; o2 <<= 1) part += __shfl_xor(part, o2, 64);
        if (r16 == 0) atomicAdd(&xsum[(long)bz * N_ + row], part * (1.0f / H_));
      }
    }
}

// ---------------------------------------------------------------------------
// K2: x1 = relu(dis_i*(sum_{bit j} dis_j*P1_j + dis_i*P1_i) + b1)
// bitmask-driven; wave-level scan; fused t[row] = x1_row . Watt
// ---------------------------------------------------------------------------
__global__ __launch_bounds__(256) void k_spmm_relu(
    const u64* __restrict__ bm, const float* __restrict__ P1,
    const float* __restrict__ dis_bin, const float* __restrict__ b1,
    const float* __restrict__ Watt, float* __restrict__ x1,
    float* __restrict__ t) {
  long row = blockIdx.x;
  int b = (int)(row >> 10), i = (int)(row & 1023);
  const float* Pb = P1 + (long)b * (long)N_ * H_;
  const float* db = dis_bin + (long)b * N_;
  __shared__ int idxs[N_];
  __shared__ int wtot[4];
  __shared__ float accs[H_];
  int tid = threadIdx.x;
  int wid = tid >> 6, lane = tid & 63;
  int base = tid * 4;
  u64 word = bm[row * 16 + (tid >> 4)];
  int sh = base & 63;
  int f0 = (int)((word >> sh) & 1), f1 = (int)((word >> (sh + 1)) & 1);
  int f2 = (int)((word >> (sh + 2)) & 1), f3 = (int)((word >> (sh + 3)) & 1);
  int c0 = f0 + f1 + f2 + f3;
  int inc = c0;
  #pragma unroll
  for (int o = 1; o < 64; o <<= 1) {
    int v = __shfl_up(inc, o, 64);
    if (lane >= o) inc += v;
  }
  if (lane == 63) wtot[wid] = inc;
  __syncthreads();
  int wbase = 0;
  #pragma unroll
  for (int w = 0; w < 4; ++w) wbase += (w < wid) ? wtot[w] : 0;
  int pos = wbase + inc - c0;
  int n = wtot[0] + wtot[1] + wtot[2] + wtot[3];
  if (f0) idxs[pos++] = base;
  if (f1) idxs[pos++] = base + 1;
  if (f2) idxs[pos++] = base + 2;
  if (f3) idxs[pos++] = base + 3;
  __syncthreads();
  int c = tid & 127, team = tid >> 7;
  float acc = 0.f;
  for (int u = team; u < n; u += 2) {
    int j = idxs[u];
    acc += db[j] * Pb[(long)j * H_ + c];
  }
  if (team == 1) accs[c] = acc;
  __syncthreads();
  float v = 0.f;
  if (team == 0) {
    float di = db[i];
    float tot = acc + accs[c] + di * Pb[(long)i * H_ + c];
    v = fmaxf(di * tot + b1[c], 0.0f);
    x1[row * H_ + c] = v;
  }
  __syncthreads();
  float prod = (team == 0) ? v * Watt[c] : 0.f;
  float s = blockReduceSum256(prod);
  if (tid == 0) t[row] = s;
}

// ---------------------------------------------------------------------------
// K5: alpha (bitmask-driven)
// ---------------------------------------------------------------------------
__global__ __launch_bounds__(256) void k_alpha(
    const u64* __restrict__ bm, const float* __restrict__ dis_bin,
    const float* __restrict__ t, const float* __restrict__ batt,
    float* __restrict__ alpha) {
  long row = blockIdx.x;
  int b = (int)(row >> 10), i = (int)(row & 1023);
  const float* db = dis_bin + (long)b * N_;
  const float* tb = t + (long)b * N_;
  int tid = threadIdx.x;
  float s = 0.f;
  #pragma unroll
  for (int it = 0; it < 4; ++it) {
    int j = tid + it * 256;
    u64 word = bm[row * 16 + (j >> 6)];
    if ((word >> (j & 63)) & 1) s += db[j] * tb[j];
  }
  s = blockReduceSum256(s);
  if (tid == 0) {
    float di = db[i];
    float pre = di * (s + di * tb[i]) + batt[0];
    float z = pre * pre;
    alpha[row] = 1.0f / (1.0f + expf(-z));
  }
}

// ---------------------------------------------------------------------------
// K6: top-k cut + mask (exact stable-sort semantics via composite key)
// ---------------------------------------------------------------------------
__global__ __launch_bounds__(1024) void k_cutmask2(
    const float* __restrict__ alpha, const int* __restrict__ num_sent,
    const int* __restrict__ nout, float* __restrict__ index_mask,
    float* __restrict__ ca) {
  int b = blockIdx.x, tid = threadIdx.x;
  __shared__ u64 keys[N_];
  __shared__ u64 red[N_];
  int ns = num_sent[b];
  float av = alpha[(long)b * N_ + tid];
  unsigned bits = __float_as_uint(av);
  u64 keyFull = ((u64)bits << 32) | (u64)(0xFFFFFFFFu - (unsigned)tid);
  keys[tid] = (tid < ns) ? keyFull : 0ULL;
  __syncthreads();
  int k = nout[0];
  u64 cutkey = 0;
  for (int r = 0; r < k; ++r) {
    red[tid] = keys[tid];
    __syncthreads();
    for (int off = 512; off > 0; off >>= 1) {
      if (tid < off) { u64 o = red[tid + off]; if (o > red[tid]) red[tid] = o; }
      __syncthreads();
    }
    u64 mx = red[0];
    __syncthreads();
    if (r == k - 1) cutkey = mx;
    else if (keys[tid] == mx) keys[tid] = 0ULL;
    __syncthreads();
  }
  float cutalpha = __uint_as_float((unsigned)(cutkey >> 32));
  index_mask[(long)b * N_ + tid] = (keyFull >= cutkey) ? 1.0f : 0.0f;
  ca[(long)b * N_ + tid] = fmaxf(av + 1e-7f - cutalpha, 0.0f);
}

// ---------------------------------------------------------------------------
// K7: S build + L1 row-normalize (reads bf16 adj; register-resident row)
// ---------------------------------------------------------------------------
__global__ __launch_bounds__(256) void k_build_S(
    const u16* __restrict__ abf, const float* __restrict__ dr,
    const float* __restrict__ dc, const float* __restrict__ ca,
    float* __restrict__ S) {
  long row = blockIdx.x;
  int b = (int)(row >> 10), i = (int)(row & 1023);
  const u16* a = abf + row * N_;
  const float* dcb = dc + (long)b * N_;
  const float* cab = ca + (long)b * N_;
  float dri = dr[row];
  int tid = threadIdx.x;
  u16x4 av4 = *(const u16x4*)(a + tid * 4);
  f32x4 dc4 = *(const f32x4*)(dcb + tid * 4);
  f32x4 ca4 = *(const f32x4*)(cab + tid * 4);
  float ls = 0.f;
  f32x4 pv;
  #pragma unroll
  for (int e = 0; e < 4; ++e) {
    int j = tid * 4 + e;
    float avv = b2f(av4[e]) + ((j == i) ? 1.0f : 0.0f);
    float v = dri * avv * dc4[e] * ca4[e];
    pv[e] = v;
    ls += v;
  }
  float sum = blockReduceSum256(ls);
  float denom = fmaxf(sum, 1e-12f);
  f32x4 out;
  #pragma unroll
  for (int e = 0; e < 4; ++e) out[e] = pv[e] / denom;
  *(f32x4*)(&S[row * N_ + tid * 4]) = out;
}

// ---------------------------------------------------------------------------
// Big MFMA GEMM: 128x128 tile, BK=32, global_load_lds staging, XCD swizzle.
// MODE 1: bf16 C | 2: floorq + rowcnt + cbin(diag+1) |
// 3: f32 ftanh(rsqrt(1+cnt[row])*acc + bias[col]) + xs1 atomics |
// 5: bf16 f2b(rsqrt(1+cnt[col])*acc)
// ---------------------------------------------------------------------------
template<int MODE>
__global__ __launch_bounds__(256) void mgemm(
    const u16* __restrict__ A, const u16* __restrict__ Bt, void* __restrict__ Cv,
    int M, int N, int K, long sA, long sB, long sC, long ldb,
    const int* __restrict__ cnt, const float* __restrict__ bias,
    int* __restrict__ rowcnt, u16* __restrict__ cbin,
    float* __restrict__ xsum) {
  // XCD-aware bijective chunked remap (total blocks divisible by 8)
  int gx = gridDim.x, gy = gridDim.y;
  int lin = (blockIdx.z * gy + blockIdx.y) * gx + blockIdx.x;
  int total = gx * gy * gridDim.z;
  int chunk = total >> 3;
  int swz = (lin & 7) * chunk + (lin >> 3);
  int bx = swz % gx; int t2 = swz / gx; int by = t2 % gy; int bz = t2 / gy;

  int m0 = by * 128, n0 = bx * 128;
  const u16* Ab = A + (long)bz * sA + (long)m0 * K;
  const u16* Bb = Bt + (long)bz * sB + (long)n0 * ldb;
  __shared__ __align__(16) u16 As[128 * 32];
  __shared__ __align__(16) u16 Bs[128 * 32];
  int tid = threadIdx.x;
  int lane = tid & 63, wave = tid >> 6;
  int wr = wave >> 1, wc = wave & 1;
  int kg = lane >> 4, r16 = lane & 15;
  const u16* ga = Ab + (long)(tid >> 2) * K + (tid & 3) * 8;
  const u16* gb = Bb + (long)(tid >> 2) * ldb + (tid & 3) * 8;
  f32x4 acc[4][4] = {};

  for (int k0 = 0; k0 < K; k0 += 32) {
    gload16(ga + k0, &As[tid * 8]);
    gload16(ga + (long)64 * K + k0, &As[2048 + tid * 8]);
    gload16(gb + k0, &Bs[tid * 8]);
    gload16(gb + (long)64 * ldb + k0, &Bs[2048 + tid * 8]);
    __syncthreads();
    s16x8 af[4], bfr[4];
    #pragma unroll
    for (int m = 0; m < 4; ++m)
      af[m] = *(const s16x8*)(&As[(wr * 64 + m * 16 + r16) * 32 + kg * 8]);
    #pragma unroll
    for (int n = 0; n < 4; ++n)
      bfr[n] = *(const s16x8*)(&Bs[(wc * 64 + n * 16 + r16) * 32 + kg * 8]);
    #pragma unroll
    for (int m = 0; m < 4; ++m)
      #pragma unroll
      for (int n = 0; n < 4; ++n)
        acc[m][n] = __builtin_amdgcn_mfma_f32_16x16x32_bf16(af[m], bfr[n], acc[m][n], 0, 0, 0);
    __syncthreads();
  }

  if constexpr (MODE == 2) {
    int* cntl = (int*)As;
    if (tid < 128) cntl[tid] = 0;
    __syncthreads();
    #pragma unroll
    for (int m = 0; m < 4; ++m) {
      #pragma unroll
      for (int r = 0; r < 4; ++r) {
        int lrow = wr * 64 + m * 16 + kg * 4 + r;
        int row = m0 + lrow;
        int nz = 0;
        #pragma unroll
        for (int n = 0; n < 4; ++n) {
          int col = n0 + wc * 64 + n * 16 + r16;
          float q = floorf(acc[m][n][r] * 10000.0f) / 10000.0f;
          long cidx = (long)bz * sC + (long)row * N + col;
          ((float*)Cv)[cidx] = q;
          bool qnz = (q != 0.0f);
          u16 bv;
          if (row == col) bv = qnz ? (u16)0x4000 : (u16)0x3F80;  // bin+I diag
          else            bv = qnz ? (u16)0x3F80 : (u16)0;
          cbin[cidx] = bv;
          nz += qnz ? 1 : 0;
        }
        atomicAdd(&cntl[lrow], nz);
      }
    }
    __syncthreads();
    if (tid < 128) atomicAdd(&rowcnt[(long)bz * N_ + m0 + tid], cntl[tid]);
    return;
  }

  #pragma unroll
  for (int m = 0; m < 4; ++m) {
    #pragma unroll
    for (int r = 0; r < 4; ++r) {
      int row = m0 + wr * 64 + m * 16 + kg * 4 + r;
      float sc = 0.f;
      if constexpr (MODE == 3)
        sc = rsqrtf(1.0f + (float)cnt[(long)bz * N_ + row]);
      float part = 0.f;
      #pragma unroll
      for (int n = 0; n < 4; ++n) {
        int col = n0 + wc * 64 + n * 16 + r16;
        float v = acc[m][n][r];
        long cidx = (long)bz * sC + (long)row * N + col;
        if constexpr (MODE == 1) {
          ((u16*)Cv)[cidx] = f2b(v);
        } else if constexpr (MODE == 3) {
          float th = ftanh(sc * v + bias[col]);
          ((float*)Cv)[cidx] = th;
          part += th;
        } else if constexpr (MODE == 5) {
          float scc = rsqrtf(1.0f + (float)cnt[col]);
          ((u16*)Cv)[cidx] = f2b(scc * v);
        } else {
          ((float*)Cv)[cidx] = v;
        }
      }
      if constexpr (MODE == 3) {
        #pragma unroll
        for (int o2 = 1; o2 < 16; o2 <<= 1) part += __shfl_xor(part, o2, 64);
        if (r16 == 0) atomicAdd(&xsum[(long)bz * N_ + row], part * (1.0f / F_));
      }
    }
  }
}

// ---------------------------------------------------------------------------
// transpose-convert: X[b][R][C] f32 -> Y[b][C][R] bf16 (LDS-staged, coalesced)
// ---------------------------------------------------------------------------
__global__ __launch_bounds__(256) void k_convT(
    const float* __restrict__ X, u16* __restrict__ Y, int R, int C,
    long sX, long sY) {
  __shared__ float tile[32][33];
  const float* Xb = X + (long)blockIdx.z * sX;
  u16* Yb = Y + (long)blockIdx.z * sY;
  int tx = threadIdx.x & 31, ty = threadIdx.x >> 5;
  int r0 = blockIdx.y * 32, c0 = blockIdx.x * 32;
  #pragma unroll
  for (int i = 0; i < 4; ++i)
    tile[ty + i * 8][tx] = Xb[(long)(r0 + ty + i * 8) * C + (c0 + tx)];
  __syncthreads();
  #pragma unroll
  for (int i = 0; i < 4; ++i)
    Yb[(long)(c0 + ty + i * 8) * R + (r0 + tx)] = f2b(tile[tx][ty + i * 8]);
}

// ---------------------------------------------------------------------------
extern "C" void kernel_launch(void* const* d_in, const int* in_sizes, int n_in,
                              void* d_out, int out_size, void* d_ws, size_t ws_size,
                              hipStream_t stream) {
  const float* x     = (const float*)d_in[0];
  const float* adj   = (const float*)d_in[1];
  const int*   nsent = (const int*)d_in[2];
  const float* W1    = (const float*)d_in[3];
  const float* b1    = (const float*)d_in[4];
  const float* Watt  = (const float*)d_in[5];
  const float* batt  = (const float*)d_in[6];
  const float* W2    = (const float*)d_in[7];
  const float* b2    = (const float*)d_in[8];
  const int*   nout  = (const int*)d_in[9];

  const long NN = (long)N_ * N_;
  const long NH = (long)N_ * H_;
  const long NF = (long)N_ * F_;
  const int BN = B_ * N_;

  // output layout (flat concat, f32)
  float* out_x2   = (float*)d_out;
  float* out_cx   = out_x2 + (long)B_ * NF;
  float* out_cadj = out_cx + (long)B_ * NH;
  float* out_S    = out_cadj + (long)B_ * NN;
  float* out_im   = out_S + (long)B_ * NN;
  float* out_xs0  = out_im + BN;
  float* out_xs1  = out_xs0 + BN;

  // workspace (~142MB, proven scale)
  char* wsb = (char*)d_ws;
  float* P1      = (float*)wsb;
  float* x1      = P1 + (long)B_ * NH;
  float* t       = x1 + (long)B_ * NH;
  float* alpha   = t + BN;
  float* dis_bin = alpha + BN;
  float* dr      = dis_bin + BN;
  float* dc      = dr + BN;
  float* ca      = dc + BN;
  int*   rowcnt  = (int*)(ca + BN);
  u64*   bm      = (u64*)(rowcnt + BN);       // 2MB bitmask
  char*  p       = (char*)(bm + (long)BN * 16);
  p = (char*)(((size_t)p + 255) & ~(size_t)255);
  u16* W1h   = (u16*)p;  p += (long)H_ * F_ * 2;
  u16* W1m   = (u16*)p;  p += (long)H_ * F_ * 2;
  u16* W1l   = (u16*)p;  p += (long)H_ * F_ * 2;
  u16* W2T   = (u16*)p;  p += (long)H_ * F_ * 2;
  u16* PT    = (u16*)p;  p += (long)B_ * NH * 2;   // x1T
  u16* St    = (u16*)p;  p += (long)B_ * NN * 2;   // xh -> St -> P2T
  u16* adjBF = (u16*)p;  p += (long)B_ * NN * 2;   // xm -> adj_bf -> cbin
  u16* xl3   = (u16*)p;                             // xl plane (24MB)
  u16* xh    = St;
  u16* xm    = adjBF;
  u16* xl    = xl3;
  u16* cx_bf = (u16*)P1;       // P1 dead after spmm
  u16* x1T   = PT;
  u16* cbin  = adjBF;          // adj_bf dead after G6'
  u16* P2T   = St;             // St dead after G7'
  u16* M1t   = (u16*)out_x2;   // scratch in unwritten output region (32MB)

  // zero xs0/xs1 (contiguous) for epilogue atomics
  hipMemsetAsync(out_xs0, 0, (size_t)2 * BN * 4, stream);

  // K0: split x into 3 planes + transpose-split W1 (merged)
  k_prep<<<dim3(2048 + 96), dim3(256), 0, stream>>>(
      x, xh, xm, xl, (long)B_ * NF / 4, W1, W1h, W1m, W1l);

  // G1: P1raw = x @ W1  (split-3, gload-staged 128x64 tile; dis applied in K2)
  mgemmW<3, 0><<<dim3(H_ / 64, BN / 128, 1), dim3(256), 0, stream>>>(
      xh, xm, xl, W1h, W1m, W1l, P1, H_, F_, 0, 0, 0, nullptr, nullptr);

  // K1: degrees + bitmask + adj_bf + rowcnt zeroing
  k_degrees<<<dim3(BN), dim3(256), 0, stream>>>(adj, dis_bin, dr, dc, bm, adjBF, rowcnt);

  // K2: x1 + fused t (bitmask, wave scan)
  k_spmm_relu<<<dim3(BN), dim3(256), 0, stream>>>(bm, P1, dis_bin, b1, Watt, x1, t);

  // alpha + top-k cut/mask + S (S from bf16 adj)
  k_alpha<<<dim3(BN), dim3(256), 0, stream>>>(bm, dis_bin, t, batt, alpha);
  k_cutmask2<<<dim3(B_), dim3(1024), 0, stream>>>(alpha, nsent, nout, out_im, ca);
  k_build_S<<<dim3(BN), dim3(256), 0, stream>>>(adjBF, dr, dc, ca, out_S);

  // transposes: St, x1T
  k_convT<<<dim3(N_ / 32, N_ / 32, B_), dim3(256), 0, stream>>>(out_S, St, N_, N_, NN, NN);
  k_convT<<<dim3(H_ / 32, N_ / 32, B_), dim3(256), 0, stream>>>(x1, x1T, N_, H_, NH, NH);

  // G5: coarse_x = S^T @ x1 + fused cx_bf + xs0 row-means
  mgemmW<1, 1><<<dim3(H_ / 64, N_ / 128, B_), dim3(256), 0, stream>>>(
      St, St, St, x1T, x1T, x1T, out_cx, H_, N_, NN, NH, NH, cx_bf, out_xs0);

  // G6': M1^T = S^T @ adj^T = (adj @ S)^T   (A=St, Bt=adj_bf, bf16 out)
  mgemm<1><<<dim3(N_ / 128, N_ / 128, B_), dim3(256), 0, stream>>>(
      St, adjBF, M1t, N_, N_, N_, NN, NN, NN, N_, nullptr, nullptr, nullptr,
      nullptr, nullptr);

  // G7': coarse_adj = floorq(S^T @ M1) + rowcnt + cbin(diag+1)
  mgemm<2><<<dim3(N_ / 128, N_ / 128, B_), dim3(256), 0, stream>>>(
      St, M1t, out_cadj, N_, N_, N_, NN, NN, NN, N_, nullptr, nullptr, rowcnt,
      cbin, nullptr);

  // W2T  [F][H] bf16
  k_convT<<<dim3(F_ / 32, H_ / 32, 1), dim3(256), 0, stream>>>(W2, W2T, H_, F_, 0, 0);

  // G8' (transposed role): P2T[f][r] = f2b(rsqrt(1+cnt[r]) * (W2T[f] . cx_bf[r]))
  mgemm<5><<<dim3(BN / 128, F_ / 128, 1), dim3(256), 0, stream>>>(
      W2T, cx_bf, P2T, F_, BN, H_, 0, 0, 0, H_, rowcnt, nullptr, nullptr,
      nullptr, nullptr);

  // G9: x2 = ftanh(rsqrt(1+cnt[row]) * (cbin' @ P2) + b2) + xs1 row-means
  mgemm<3><<<dim3(F_ / 128, N_ / 128, B_), dim3(256), 0, stream>>>(
      cbin, P2T, out_x2, N_, F_, N_, NN, N_, NF, (long)BN, rowcnt, b2,
      nullptr, nullptr, out_xs1);
}